// Round 12
// baseline (288.251 us; speedup 1.0000x reference)
//
#include <hip/hip_runtime.h>
#include <math.h>

#define EPS 1e-5f

constexpr int Bb  = 128;
constexpr int C   = 256;
constexpr int Nz  = 169;   // 13*13
constexpr int Nx  = 625;   // 25*25
constexpr int NzP = 192;   // Nz padded (zero-filled)

typedef __bf16 bf16x8 __attribute__((ext_vector_type(8)));
typedef float  f32x4  __attribute__((ext_vector_type(4)));

__device__ __forceinline__ unsigned short f2bf(float f) {
    union { float f; unsigned u; } x; x.f = f;
    unsigned r = x.u + 0x7FFFu + ((x.u >> 16) & 1u);   // RNE
    return (unsigned short)(r >> 16);
}
__device__ __forceinline__ float bf2f(unsigned short h) {
    union { unsigned u; float f; } x; x.u = ((unsigned)h) << 16;
    return x.f;
}

// ---------------------------------------------------------------------------
// Wg, Wf → bf16
// ---------------------------------------------------------------------------
__global__ void cvt_wgf(const float* __restrict__ Wg, const float* __restrict__ Wf,
                        unsigned short* __restrict__ g, unsigned short* __restrict__ f)
{
    int i = blockIdx.x * 256 + threadIdx.x;
    if (i < C * C) g[i] = f2bf(Wg[i]);
    if (i < C * 2 * C) f[i] = f2bf(Wf[i]);
}

// ---------------------------------------------------------------------------
// wv = Wq^T bs, wu = Ws^T bq, c0 = bq.bs
// ---------------------------------------------------------------------------
__global__ void prep_small(const float* __restrict__ Wq, const float* __restrict__ Ws,
                           const float* __restrict__ bq, const float* __restrict__ bs,
                           float* __restrict__ wv, float* __restrict__ wu,
                           float* __restrict__ c0)
{
    const int tid = threadIdx.x;
    float a = 0.f, b = 0.f;
    for (int o = 0; o < C; ++o) {
        a += Wq[o * C + tid] * bs[o];
        b += Ws[o * C + tid] * bq[o];
    }
    wv[tid] = a;
    wu[tid] = b;
    if (tid == 0) {
        float c = 0.f;
        for (int o = 0; o < C; ++o) c += bq[o] * bs[o];
        c0[0] = c;
    }
}

// ---------------------------------------------------------------------------
// M = Wq^T Ws  (fp32 compute, split bf16 hi/lo output).  grid (4,4)
// ---------------------------------------------------------------------------
__global__ __launch_bounds__(256)
void m_gemm(const float* __restrict__ Wq, const float* __restrict__ Ws,
            unsigned short* __restrict__ Mhi, unsigned short* __restrict__ Mlo)
{
    __shared__ float Qs[16][65], Ss[16][65];
    const int j0 = blockIdx.x * 64, i0 = blockIdx.y * 64;
    const int tid = threadIdx.x, tx = tid & 15, ty = tid >> 4;
    float acc[4][4] = {};

    for (int kc = 0; kc < C; kc += 16) {
        #pragma unroll
        for (int i = 0; i < 4; ++i) {
            int e = tid + 256 * i;
            int k = e >> 6, col = e & 63;
            Qs[k][col] = Wq[(size_t)(kc + k) * C + i0 + col];
            Ss[k][col] = Ws[(size_t)(kc + k) * C + j0 + col];
        }
        __syncthreads();
        #pragma unroll
        for (int k = 0; k < 16; ++k) {
            float a[4], bv[4];
            #pragma unroll
            for (int i = 0; i < 4; ++i) a[i] = Qs[k][ty * 4 + i];
            #pragma unroll
            for (int j = 0; j < 4; ++j) bv[j] = Ss[k][tx * 4 + j];
            #pragma unroll
            for (int i = 0; i < 4; ++i)
                #pragma unroll
                for (int j = 0; j < 4; ++j)
                    acc[i][j] = fmaf(a[i], bv[j], acc[i][j]);
        }
        __syncthreads();
    }
    #pragma unroll
    for (int i = 0; i < 4; ++i)
        #pragma unroll
        for (int j = 0; j < 4; ++j) {
            float v = acc[i][j];
            unsigned short h = f2bf(v);
            size_t idx = (size_t)(i0 + ty * 4 + i) * C + j0 + tx * 4 + j;
            Mhi[idx] = h;
            Mlo[idx] = f2bf(v - bf2f(h));
        }
}

// ---------------------------------------------------------------------------
// u[b,m] = wu . zf[b,:,m] + c0
// ---------------------------------------------------------------------------
__global__ void bias_u(const float* __restrict__ zf, const float* __restrict__ wu,
                       const float* __restrict__ c0, float* __restrict__ U)
{
    const int b = blockIdx.x, m = threadIdx.x;
    if (m >= NzP) return;
    float s = 0.f;
    if (m < Nz) {
        const float* zb = zf + (size_t)b * C * Nz + m;
        float s0 = 0.f, s1 = 0.f, s2 = 0.f, s3 = 0.f;
        for (int c = 0; c < C; c += 4) {
            s0 += wu[c]     * zb[(size_t)c * Nz];
            s1 += wu[c + 1] * zb[(size_t)(c + 1) * Nz];
            s2 += wu[c + 2] * zb[(size_t)(c + 2) * Nz];
            s3 += wu[c + 3] * zb[(size_t)(c + 3) * Nz];
        }
        s = (s0 + s1) + (s2 + s3) + c0[0];
    }
    U[(size_t)b * NzP + m] = s;
}

// ---------------------------------------------------------------------------
// zf [b][C][Nz] f32  →  hi/lo bf16 [b][Nz][C]
// ---------------------------------------------------------------------------
__global__ __launch_bounds__(256)
void x2t_split(const float* __restrict__ X, unsigned short* __restrict__ Hi,
               unsigned short* __restrict__ Lo, int N)
{
    __shared__ float T[64][65];
    const int b = blockIdx.z, n0 = blockIdx.x * 64, c0 = blockIdx.y * 64;
    const float* Xb = X + ((size_t)b * C + c0) * N;
    #pragma unroll
    for (int i = 0; i < 16; ++i) {
        int e = threadIdx.x + 256 * i;
        int c = e >> 6, n = e & 63;
        T[c][n] = (n0 + n < N) ? Xb[(size_t)c * N + n0 + n] : 0.f;
    }
    __syncthreads();
    #pragma unroll
    for (int i = 0; i < 16; ++i) {
        int e = threadIdx.x + 256 * i;
        int n = e >> 6, c = e & 63;
        if (n0 + n < N) {
            float v = T[c][n];
            unsigned short h = f2bf(v);
            size_t idx = ((size_t)b * N + n0 + n) * C + c0 + c;
            Hi[idx] = h;
            Lo[idx] = f2bf(v - bf2f(h));
        }
    }
}

// ---------------------------------------------------------------------------
// Split-bf16 MFMA GEMM — z-side zq' = M zf + wv.
// ---------------------------------------------------------------------------
__global__ __launch_bounds__(256)
void mfma_split(const unsigned short* __restrict__ Ahi,
                const unsigned short* __restrict__ Alo, size_t aStride,
                const unsigned short* __restrict__ Bhi,
                const unsigned short* __restrict__ Blo,
                const float* __restrict__ bias,
                unsigned short* __restrict__ Yhi, unsigned short* __restrict__ Ylo,
                int N, int Nout, int K, int O)
{
    __shared__ unsigned short Ah[64][40], Al[64][40], Bh[64][40], Bl[64][40];

    const int b   = blockIdx.z;
    const int n0  = blockIdx.x * 64;
    const int o0  = blockIdx.y * 64;
    const int tid = threadIdx.x;
    const int lane = tid & 63, wid = tid >> 6;
    const int wr = wid >> 1, wc = wid & 1;

    const unsigned short* Ahb = Ahi + (size_t)b * aStride;
    const unsigned short* Alb = Alo + (size_t)b * aStride;
    const unsigned short* Bhb = Bhi + (size_t)b * N * K;
    const unsigned short* Blb = Blo + (size_t)b * N * K;

    f32x4 acc[2][2];
    #pragma unroll
    for (int i = 0; i < 2; ++i)
        #pragma unroll
        for (int j = 0; j < 2; ++j)
            #pragma unroll
            for (int e = 0; e < 4; ++e) acc[i][j][e] = 0.f;

    const int srow = tid >> 2, sseg = tid & 3;
    const int lr = lane & 15, lk = (lane >> 4) * 8;

    for (int kc = 0; kc < K; kc += 32) {
        const int gk = kc + sseg * 8;
        *(int4*)&Ah[srow][sseg * 8] = *(const int4*)&Ahb[(size_t)(o0 + srow) * K + gk];
        *(int4*)&Al[srow][sseg * 8] = *(const int4*)&Alb[(size_t)(o0 + srow) * K + gk];

        const int gn = n0 + srow;
        int4 bv = make_int4(0, 0, 0, 0), blv = make_int4(0, 0, 0, 0);
        if (gn < N) {
            bv  = *(const int4*)&Bhb[(size_t)gn * K + gk];
            blv = *(const int4*)&Blb[(size_t)gn * K + gk];
        }
        *(int4*)&Bh[srow][sseg * 8] = bv;
        *(int4*)&Bl[srow][sseg * 8] = blv;
        __syncthreads();

        bf16x8 ah[2], al[2], bh[2], bl[2];
        #pragma unroll
        for (int i = 0; i < 2; ++i) {
            ah[i] = *(const bf16x8*)&Ah[wr * 32 + i * 16 + lr][lk];
            al[i] = *(const bf16x8*)&Al[wr * 32 + i * 16 + lr][lk];
            bh[i] = *(const bf16x8*)&Bh[wc * 32 + i * 16 + lr][lk];
            bl[i] = *(const bf16x8*)&Bl[wc * 32 + i * 16 + lr][lk];
        }
        #pragma unroll
        for (int i = 0; i < 2; ++i)
            #pragma unroll
            for (int j = 0; j < 2; ++j) {
                acc[i][j] = __builtin_amdgcn_mfma_f32_16x16x32_bf16(al[i], bh[j], acc[i][j], 0, 0, 0);
                acc[i][j] = __builtin_amdgcn_mfma_f32_16x16x32_bf16(ah[i], bl[j], acc[i][j], 0, 0, 0);
                acc[i][j] = __builtin_amdgcn_mfma_f32_16x16x32_bf16(ah[i], bh[j], acc[i][j], 0, 0, 0);
            }
        __syncthreads();
    }

    const int lg = lane >> 4;
    #pragma unroll
    for (int i = 0; i < 2; ++i) {
        const int ob = o0 + wr * 32 + i * 16 + lg * 4;
        float bi[4];
        #pragma unroll
        for (int r = 0; r < 4; ++r) bi[r] = bias[ob + r];
        #pragma unroll
        for (int j = 0; j < 2; ++j) {
            const int gn = n0 + wc * 32 + j * 16 + lr;
            if (gn < Nout) {
                uint2 ph = make_uint2(0, 0), pl = make_uint2(0, 0);
                if (gn < N) {
                    unsigned short h[4], l[4];
                    #pragma unroll
                    for (int r = 0; r < 4; ++r) {
                        float v = acc[i][j][r] + bi[r];
                        h[r] = f2bf(v);
                        l[r] = f2bf(v - bf2f(h[r]));
                    }
                    ph.x = (unsigned)h[0] | ((unsigned)h[1] << 16);
                    ph.y = (unsigned)h[2] | ((unsigned)h[3] << 16);
                    pl.x = (unsigned)l[0] | ((unsigned)l[1] << 16);
                    pl.y = (unsigned)l[2] | ((unsigned)l[3] << 16);
                }
                size_t idx = ((size_t)b * Nout + gn) * O + ob;
                *(uint2*)&Yhi[idx] = ph;
                *(uint2*)&Ylo[idx] = pl;
            }
        }
    }
}

// ---------------------------------------------------------------------------
// Plain bf16 MFMA GEMM (z-side small: zf_g conv, zg2).
// ---------------------------------------------------------------------------
template<int MODE, int EPI>
__global__ __launch_bounds__(256)
void mfma_conv(const unsigned short* __restrict__ A, int aLd, size_t aStride,
               const unsigned short* __restrict__ B1,
               const float* __restrict__ bias, const float* __restrict__ gamma,
               const float* __restrict__ beta, const float* __restrict__ mean,
               const float* __restrict__ var,
               unsigned short* __restrict__ Y, int N, int Nout, int K, int O)
{
    __shared__ unsigned short As[64][40];
    __shared__ unsigned short Bs[64][40];

    const int b   = blockIdx.z;
    const int n0  = blockIdx.x * 64;
    const int o0  = blockIdx.y * 64;
    const int tid = threadIdx.x;
    const int lane = tid & 63, wid = tid >> 6;
    const int wr = wid >> 1, wc = wid & 1;

    const unsigned short* Ab  = A + (size_t)b * aStride;
    const unsigned short* B1b = B1 + (size_t)b * N * K;

    f32x4 acc[2][2];
    #pragma unroll
    for (int i = 0; i < 2; ++i)
        #pragma unroll
        for (int j = 0; j < 2; ++j)
            #pragma unroll
            for (int e = 0; e < 4; ++e) acc[i][j][e] = 0.f;

    const int srow = tid >> 2, sseg = tid & 3;
    const int lr = lane & 15, lk = (lane >> 4) * 8;

    for (int kc = 0; kc < K; kc += 32) {
        const int gk = kc + sseg * 8;
        *(int4*)&As[srow][sseg * 8] = *(const int4*)&Ab[(size_t)(o0 + srow) * aLd + gk];

        const int gn = n0 + srow;
        int4 bv = make_int4(0, 0, 0, 0);
        if (gn < N) bv = *(const int4*)&B1b[(size_t)gn * K + gk];
        *(int4*)&Bs[srow][sseg * 8] = bv;
        __syncthreads();

        bf16x8 a0 = *(const bf16x8*)&As[wr * 32 +      lr][lk];
        bf16x8 a1 = *(const bf16x8*)&As[wr * 32 + 16 + lr][lk];
        bf16x8 b0 = *(const bf16x8*)&Bs[wc * 32 +      lr][lk];
        bf16x8 b1 = *(const bf16x8*)&Bs[wc * 32 + 16 + lr][lk];

        acc[0][0] = __builtin_amdgcn_mfma_f32_16x16x32_bf16(a0, b0, acc[0][0], 0, 0, 0);
        acc[0][1] = __builtin_amdgcn_mfma_f32_16x16x32_bf16(a0, b1, acc[0][1], 0, 0, 0);
        acc[1][0] = __builtin_amdgcn_mfma_f32_16x16x32_bf16(a1, b0, acc[1][0], 0, 0, 0);
        acc[1][1] = __builtin_amdgcn_mfma_f32_16x16x32_bf16(a1, b1, acc[1][1], 0, 0, 0);
        __syncthreads();
    }

    const int lg = lane >> 4;
    #pragma unroll
    for (int i = 0; i < 2; ++i) {
        const int ob = o0 + wr * 32 + i * 16 + lg * 4;
        float inv[4], sh[4], bi[4];
        if (EPI) {
            #pragma unroll
            for (int r = 0; r < 4; ++r) {
                int o = ob + r;
                float iv = gamma[o] * rsqrtf(var[o] + EPS);
                inv[r] = iv; sh[r] = beta[o] - mean[o] * iv; bi[r] = bias[o];
            }
        }
        #pragma unroll
        for (int j = 0; j < 2; ++j) {
            const int gn = n0 + wc * 32 + j * 16 + lr;
            float v[4];
            #pragma unroll
            for (int r = 0; r < 4; ++r) {
                v[r] = acc[i][j][r];
                if (EPI) v[r] = fmaxf(fmaf(v[r] + bi[r], inv[r], sh[r]), 0.f);
            }
            if (MODE == 0) {
                if (gn < Nout) {
                    uint2 pk = make_uint2(0, 0);
                    if (gn < N) {
                        pk.x = (unsigned)f2bf(v[0]) | ((unsigned)f2bf(v[1]) << 16);
                        pk.y = (unsigned)f2bf(v[2]) | ((unsigned)f2bf(v[3]) << 16);
                    }
                    *(uint2*)&Y[((size_t)b * Nout + gn) * O + ob] = pk;
                }
            } else {
                if (gn < Nout) {
                    #pragma unroll
                    for (int r = 0; r < 4; ++r)
                        Y[((size_t)b * O + ob + r) * Nout + gn] =
                            (gn < N) ? f2bf(v[r]) : (unsigned short)0;
                }
            }
        }
    }
}

// ---------------------------------------------------------------------------
// X-side megakernel, per (b, 64-n tile). Phase order minimizes LDS peak:
//  G   : acc = Wg . xf            -> XG (LDS, XOR-swizzled [64][256])
//  P2  : acc = Wf2 . XG           (K=256, B from LDS)
//  sim : sacc = xf^T zq' + u      (split x3 MFMA, K=256)
//  sparsemax -> Ssc (LDS)         (overlays dead XG/sim staging)
//  P1  : acc += zg2 . Ssc         (K=192, B from LDS)
//  out = bn_relu(acc + bf)
// LDS pool 53,248 B + Us -> 3 blocks/CU. __launch_bounds__(256,3).
// ---------------------------------------------------------------------------
#define XGIDX(n, o) ((((n) << 8) + (o)) ^ (((n) & 7) << 3))

__global__ __launch_bounds__(256, 3)
void mega_x(const float* __restrict__ Xf,
            const unsigned short* __restrict__ Zqh,   // [b][192][256]
            const unsigned short* __restrict__ Zql,
            const unsigned short* __restrict__ Wg,    // [256][256]
            const unsigned short* __restrict__ Zg2,   // [b][256][192]
            const unsigned short* __restrict__ Wf2,   // [256][512] base+256
            const float* __restrict__ U,              // [b][192]
            const float* __restrict__ bg, const float* __restrict__ g_gamma,
            const float* __restrict__ g_beta, const float* __restrict__ g_mean,
            const float* __restrict__ g_var,
            const float* __restrict__ bf, const float* __restrict__ f_gamma,
            const float* __restrict__ f_beta, const float* __restrict__ f_mean,
            const float* __restrict__ f_var,
            float* __restrict__ out)
{
    __shared__ __attribute__((aligned(16))) char pool[53248];
    __shared__ float Us[192];

    // overlays (phase-disjoint):
    unsigned short* XG  = (unsigned short*)(pool);            // [64][256] swz, 32768 B (G-epi..P2)
    unsigned short* XFg = (unsigned short*)(pool);            // [64][40] G-loop xf staging
    unsigned short* As  = (unsigned short*)(pool + 32768);    // [256][40] A staging (G/P2/P1)
    unsigned short* XFh = (unsigned short*)(pool);            // sim staging
    unsigned short* XFl = (unsigned short*)(pool + 5120);
    unsigned short* Bzh = (unsigned short*)(pool + 10240);    // [192][40]
    unsigned short* Bzl = (unsigned short*)(pool + 25600);    // [192][40], ends 40960
    unsigned short* Ssc = (unsigned short*)(pool);            // [64][200], 25600 B (post-sim)

    // XCD-aware swizzle: 1280 blocks, 1280 % 8 == 0 -> bijective
    const int g0  = blockIdx.z * gridDim.x + blockIdx.x;
    const int rid = (g0 & 7) * 160 + (g0 >> 3);
    const int b   = rid / 10;
    const int n0  = (rid % 10) * 64;

    const int tid = threadIdx.x;
    const int lane = tid & 63, w = tid >> 6;
    const int lr = lane & 15, lg = lane >> 4, lk = lg * 8;
    const int brow = tid >> 2, bseg = tid & 3;

    const unsigned short* Zqhb = Zqh + (size_t)b * NzP * C;
    const unsigned short* Zqlb = Zql + (size_t)b * NzP * C;
    const unsigned short* Zg2b = Zg2 + (size_t)b * C * NzP;

    if (tid < 192) Us[tid] = U[(size_t)b * NzP + tid];

    f32x4 acc[4][4];
    #pragma unroll
    for (int i = 0; i < 4; ++i)
        #pragma unroll
        for (int j = 0; j < 4; ++j)
            #pragma unroll
            for (int e = 0; e < 4; ++e) acc[i][j][e] = 0.f;

    // ================= G phase: acc = Wg . xf =================
    for (int kc = 0; kc < C; kc += 32) {
        #pragma unroll
        for (int s = 0; s < 4; ++s) {
            int e = tid + 256 * s;
            int row = e >> 2, seg = e & 3;
            *(int4*)&As[row * 40 + seg * 8] = *(const int4*)&Wg[(size_t)row * C + kc + seg * 8];
        }
        {
            const int gn = min(n0 + brow, Nx - 1);
            const float* src = Xf + ((size_t)b * C + kc + bseg * 8) * Nx + gn;
            unsigned short h[8];
            #pragma unroll
            for (int e = 0; e < 8; ++e) h[e] = f2bf(src[(size_t)e * Nx]);
            uint4 ph;
            ph.x = (unsigned)h[0] | ((unsigned)h[1] << 16);
            ph.y = (unsigned)h[2] | ((unsigned)h[3] << 16);
            ph.z = (unsigned)h[4] | ((unsigned)h[5] << 16);
            ph.w = (unsigned)h[6] | ((unsigned)h[7] << 16);
            *(uint4*)&XFg[brow * 40 + bseg * 8] = ph;
        }
        __syncthreads();

        bf16x8 a[4], bfr[4];
        #pragma unroll
        for (int i = 0; i < 4; ++i) a[i]   = *(const bf16x8*)&As[(w * 64 + i * 16 + lr) * 40 + lk];
        #pragma unroll
        for (int j = 0; j < 4; ++j) bfr[j] = *(const bf16x8*)&XFg[(j * 16 + lr) * 40 + lk];
        #pragma unroll
        for (int i = 0; i < 4; ++i)
            #pragma unroll
            for (int j = 0; j < 4; ++j)
                acc[i][j] = __builtin_amdgcn_mfma_f32_16x16x32_bf16(a[i], bfr[j], acc[i][j], 0, 0, 0);
        __syncthreads();
    }

    // G epilogue: bn_relu -> XG (XOR-swizzled), then zero acc
    #pragma unroll
    for (int i = 0; i < 4; ++i) {
        const int ob = w * 64 + i * 16 + lg * 4;
        float inv[4], sh[4], bi[4];
        #pragma unroll
        for (int r = 0; r < 4; ++r) {
            int o = ob + r;
            float iv = g_gamma[o] * rsqrtf(g_var[o] + EPS);
            inv[r] = iv; sh[r] = g_beta[o] - g_mean[o] * iv; bi[r] = bg[o];
        }
        #pragma unroll
        for (int j = 0; j < 4; ++j) {
            const int n = j * 16 + lr;
            unsigned short h[4];
            #pragma unroll
            for (int r = 0; r < 4; ++r)
                h[r] = f2bf(fmaxf(fmaf(acc[i][j][r] + bi[r], inv[r], sh[r]), 0.f));
            uint2 pk;
            pk.x = (unsigned)h[0] | ((unsigned)h[1] << 16);
            pk.y = (unsigned)h[2] | ((unsigned)h[3] << 16);
            *(uint2*)&XG[XGIDX(n, ob)] = pk;
        }
    }
    #pragma unroll
    for (int i = 0; i < 4; ++i)
        #pragma unroll
        for (int j = 0; j < 4; ++j)
            #pragma unroll
            for (int e = 0; e < 4; ++e) acc[i][j][e] = 0.f;
    __syncthreads();

    // ================= P2: acc = Wf2 . XG (K=256, B from LDS) =================
    for (int kc = 0; kc < C; kc += 32) {
        #pragma unroll
        for (int s = 0; s < 4; ++s) {
            int e = tid + 256 * s;
            int row = e >> 2, seg = e & 3;
            *(int4*)&As[row * 40 + seg * 8] = *(const int4*)&Wf2[(size_t)row * 512 + kc + seg * 8];
        }
        __syncthreads();

        bf16x8 a[4], bfr[4];
        #pragma unroll
        for (int i = 0; i < 4; ++i) a[i]   = *(const bf16x8*)&As[(w * 64 + i * 16 + lr) * 40 + lk];
        #pragma unroll
        for (int j = 0; j < 4; ++j) bfr[j] = *(const bf16x8*)&XG[XGIDX(j * 16 + lr, kc + lk)];
        #pragma unroll
        for (int i = 0; i < 4; ++i)
            #pragma unroll
            for (int j = 0; j < 4; ++j)
                acc[i][j] = __builtin_amdgcn_mfma_f32_16x16x32_bf16(a[i], bfr[j], acc[i][j], 0, 0, 0);
        __syncthreads();
    }

    // ================= sim phase (acc parked in VGPRs) =================
    {
        f32x4 sacc[12];
        #pragma unroll
        for (int j = 0; j < 12; ++j)
            #pragma unroll
            for (int e = 0; e < 4; ++e) sacc[j][e] = 0.f;

        for (int kc = 0; kc < C; kc += 32) {
            {
                const int gn = min(n0 + brow, Nx - 1);
                const float* src = Xf + ((size_t)b * C + kc + bseg * 8) * Nx + gn;
                unsigned short h[8], l[8];
                #pragma unroll
                for (int e = 0; e < 8; ++e) {
                    float v = src[(size_t)e * Nx];
                    h[e] = f2bf(v);
                    l[e] = f2bf(v - bf2f(h[e]));
                }
                uint4 ph, pl;
                ph.x = (unsigned)h[0] | ((unsigned)h[1] << 16);
                ph.y = (unsigned)h[2] | ((unsigned)h[3] << 16);
                ph.z = (unsigned)h[4] | ((unsigned)h[5] << 16);
                ph.w = (unsigned)h[6] | ((unsigned)h[7] << 16);
                pl.x = (unsigned)l[0] | ((unsigned)l[1] << 16);
                pl.y = (unsigned)l[2] | ((unsigned)l[3] << 16);
                pl.z = (unsigned)l[4] | ((unsigned)l[5] << 16);
                pl.w = (unsigned)l[6] | ((unsigned)l[7] << 16);
                *(uint4*)&XFh[brow * 40 + bseg * 8] = ph;
                *(uint4*)&XFl[brow * 40 + bseg * 8] = pl;
            }
            #pragma unroll
            for (int i = 0; i < 3; ++i) {
                const int slot = tid + 256 * i;
                const int r = slot >> 2, s = slot & 3;
                const int gk = kc + s * 8;
                *(int4*)&Bzh[r * 40 + s * 8] = *(const int4*)&Zqhb[(size_t)r * C + gk];
                *(int4*)&Bzl[r * 40 + s * 8] = *(const int4*)&Zqlb[(size_t)r * C + gk];
            }
            __syncthreads();

            bf16x8 a0h = *(const bf16x8*)&XFh[(w * 16 + lr) * 40 + lk];
            bf16x8 a0l = *(const bf16x8*)&XFl[(w * 16 + lr) * 40 + lk];
            #pragma unroll
            for (int j = 0; j < 12; ++j) {
                bf16x8 bh = *(const bf16x8*)&Bzh[(j * 16 + lr) * 40 + lk];
                bf16x8 bl = *(const bf16x8*)&Bzl[(j * 16 + lr) * 40 + lk];
                sacc[j] = __builtin_amdgcn_mfma_f32_16x16x32_bf16(a0l, bh, sacc[j], 0, 0, 0);
                sacc[j] = __builtin_amdgcn_mfma_f32_16x16x32_bf16(a0h, bl, sacc[j], 0, 0, 0);
                sacc[j] = __builtin_amdgcn_mfma_f32_16x16x32_bf16(a0h, bh, sacc[j], 0, 0, 0);
            }
            __syncthreads();
        }

        // add u[m], mask padded m
        #pragma unroll
        for (int j = 0; j < 12; ++j) {
            const int m = j * 16 + lr;
            const float uv = Us[m];
            const bool bad = (m >= Nz);
            #pragma unroll
            for (int q = 0; q < 4; ++q)
                sacc[j][q] = bad ? -1e30f : (sacc[j][q] + uv);
        }

        // row max over 12 regs + 16 lanes (m dimension)
        f32x4 mx = sacc[0];
        #pragma unroll
        for (int j = 1; j < 12; ++j)
            #pragma unroll
            for (int q = 0; q < 4; ++q) mx[q] = fmaxf(mx[q], sacc[j][q]);
        #pragma unroll
        for (int off = 1; off < 16; off <<= 1)
            #pragma unroll
            for (int q = 0; q < 4; ++q) mx[q] = fmaxf(mx[q], __shfl_xor(mx[q], off));

        // Newton on tau
        f32x4 tau;
        #pragma unroll
        for (int q = 0; q < 4; ++q) tau[q] = mx[q] - 1.0f;

        for (int it = 0; it < 16; ++it) {
            f32x4 s, cnt;
            #pragma unroll
            for (int q = 0; q < 4; ++q) { s[q] = 0.f; cnt[q] = 0.f; }
            #pragma unroll
            for (int j = 0; j < 12; ++j)
                #pragma unroll
                for (int q = 0; q < 4; ++q)
                    if (sacc[j][q] > tau[q]) { s[q] += sacc[j][q]; cnt[q] += 1.f; }
            #pragma unroll
            for (int off = 1; off < 16; off <<= 1)
                #pragma unroll
                for (int q = 0; q < 4; ++q) {
                    s[q]   += __shfl_xor(s[q], off);
                    cnt[q] += __shfl_xor(cnt[q], off);
                }
            bool adv = false;
            #pragma unroll
            for (int q = 0; q < 4; ++q) {
                float nt = (s[q] - 1.0f) / cnt[q];
                if (nt > tau[q]) { tau[q] = nt; adv = true; }
            }
            if (!__any(adv ? 1 : 0)) break;
        }

        // scores -> Ssc LDS (overwrites sim staging / dead XG; safe after sync)
        #pragma unroll
        for (int q = 0; q < 4; ++q) {
            const int n = w * 16 + 4 * lg + q;
            #pragma unroll
            for (int j = 0; j < 12; ++j) {
                const int m = j * 16 + lr;
                float sv = (m < Nz) ? fmaxf(sacc[j][q] - tau[q], 0.f) : 0.f;
                Ssc[n * 200 + m] = f2bf(sv);
            }
        }
    }
    __syncthreads();

    // ================= P1: acc += zg2 . Ssc (K=192, B from LDS) =================
    for (int kc = 0; kc < NzP; kc += 32) {
        #pragma unroll
        for (int s = 0; s < 4; ++s) {
            int e = tid + 256 * s;
            int row = e >> 2, seg = e & 3;
            *(int4*)&As[row * 40 + seg * 8] = *(const int4*)&Zg2b[(size_t)row * NzP + kc + seg * 8];
        }
        __syncthreads();

        bf16x8 a[4], bfr[4];
        #pragma unroll
        for (int i = 0; i < 4; ++i) a[i]   = *(const bf16x8*)&As[(w * 64 + i * 16 + lr) * 40 + lk];
        #pragma unroll
        for (int j = 0; j < 4; ++j) bfr[j] = *(const bf16x8*)&Ssc[(j * 16 + lr) * 200 + kc + lk];
        #pragma unroll
        for (int i = 0; i < 4; ++i)
            #pragma unroll
            for (int j = 0; j < 4; ++j)
                acc[i][j] = __builtin_amdgcn_mfma_f32_16x16x32_bf16(a[i], bfr[j], acc[i][j], 0, 0, 0);
        __syncthreads();
    }

    // final epilogue: bn_relu(f) -> out f32 [b][256][Nx]
    #pragma unroll
    for (int i = 0; i < 4; ++i) {
        const int ob = w * 64 + i * 16 + lg * 4;
        float inv[4], sh[4], bi[4];
        #pragma unroll
        for (int r = 0; r < 4; ++r) {
            int o = ob + r;
            float iv = f_gamma[o] * rsqrtf(f_var[o] + EPS);
            inv[r] = iv; sh[r] = f_beta[o] - f_mean[o] * iv; bi[r] = bf[o];
        }
        #pragma unroll
        for (int j = 0; j < 4; ++j) {
            const int gn = n0 + j * 16 + lr;
            if (gn < Nx) {
                #pragma unroll
                for (int r = 0; r < 4; ++r) {
                    float v = fmaxf(fmaf(acc[i][j][r] + bi[r], inv[r], sh[r]), 0.f);
                    out[((size_t)b * C + ob + r) * Nx + gn] = v;
                }
            }
        }
    }
}

// ---------------------------------------------------------------------------
extern "C" void kernel_launch(void* const* d_in, const int* in_sizes, int n_in,
                              void* d_out, int out_size, void* d_ws, size_t ws_size,
                              hipStream_t stream)
{
    const float* zf      = (const float*)d_in[0];
    const float* xf      = (const float*)d_in[1];
    const float* Wq      = (const float*)d_in[2];
    const float* bq      = (const float*)d_in[3];
    const float* Ws_     = (const float*)d_in[4];
    const float* bs      = (const float*)d_in[5];
    const float* Wg      = (const float*)d_in[6];
    const float* bg      = (const float*)d_in[7];
    const float* g_gamma = (const float*)d_in[8];
    const float* g_beta  = (const float*)d_in[9];
    const float* g_mean  = (const float*)d_in[10];
    const float* g_var   = (const float*)d_in[11];
    const float* Wf      = (const float*)d_in[12];
    const float* bf_     = (const float*)d_in[13];
    const float* f_gamma = (const float*)d_in[14];
    const float* f_beta  = (const float*)d_in[15];
    const float* f_mean  = (const float*)d_in[16];
    const float* f_var   = (const float*)d_in[17];
    float* out = (float*)d_out;

    typedef unsigned short u16;
    char* ws = (char*)d_ws;
    u16*   zfT_hi = (u16*)(ws);                   //  11,075,584
    u16*   zfT_lo = (u16*)(ws +  11075584);       //  11,075,584
    u16*   zqT_hi = (u16*)(ws +  22151168);       //  12,582,912
    u16*   zqT_lo = (u16*)(ws +  34734080);       //  12,582,912
    u16*   zf_gT  = (u16*)(ws +  47316992);       //  12,582,912
    u16*   zg2    = (u16*)(ws +  59899904);       //  12,582,912
    float* U      = (float*)(ws +  72482816);     //      98,304
    u16*   Mhi    = (u16*)(ws +  72581120);       //     131,072
    u16*   Mlo    = (u16*)(ws +  72712192);       //     131,072
    u16*   Wg_bf  = (u16*)(ws +  72843264);       //     131,072
    u16*   Wf_bf  = (u16*)(ws +  72974336);       //     262,144
    float* wv     = (float*)(ws +  73236480);     //       1,024
    float* wu     = (float*)(ws +  73237504);     //       1,024
    float* c0     = (float*)(ws +  73238528);     //         256

    dim3 blk(256);
    const int gx_x = (Nx + 63) / 64;   // 10
    const int gx_z = NzP / 64;         // 3

    // small precomputes
    cvt_wgf<<<dim3((C * 2 * C + 255) / 256), blk, 0, stream>>>(Wg, Wf, Wg_bf, Wf_bf);
    prep_small<<<dim3(1), blk, 0, stream>>>(Wq, Ws_, bq, bs, wv, wu, c0);
    m_gemm<<<dim3(4, 4), blk, 0, stream>>>(Wq, Ws_, Mhi, Mlo);
    bias_u<<<dim3(Bb), blk, 0, stream>>>(zf, wu, c0, U);

    // z-side transpose/split
    x2t_split<<<dim3((Nz + 63) / 64, C / 64, Bb), blk, 0, stream>>>(zf, zfT_hi, zfT_lo, Nz);

    // zq' = M zf + wv  (split)
    mfma_split<<<dim3(gx_z, C / 64, Bb), blk, 0, stream>>>(
        Mhi, Mlo, 0, zfT_hi, zfT_lo, wv, zqT_hi, zqT_lo, Nz, NzP, C, C);

    // zf_g = bn_relu(Wg . zf)
    mfma_conv<0, 1><<<dim3(gx_z, C / 64, Bb), blk, 0, stream>>>(
        Wg_bf, C, 0, zfT_hi, bg, g_gamma, g_beta, g_mean, g_var,
        zf_gT, Nz, NzP, C, C);

    // zg2 = Wf1 . zf_g   -> [b][C][NzP] bf16
    mfma_conv<1, 0><<<dim3(gx_z, C / 64, Bb), blk, 0, stream>>>(
        Wf_bf, 2 * C, 0, zf_gT, nullptr, nullptr, nullptr, nullptr, nullptr,
        zg2, NzP, NzP, C, C);

    // x-side megakernel: g-conv + final-P2 + sim + sparsemax + final-P1
    mega_x<<<dim3(gx_x, 1, Bb), blk, 0, stream>>>(
        xf, zqT_hi, zqT_lo, Wg_bf, zg2, Wf_bf + C, U,
        bg, g_gamma, g_beta, g_mean, g_var,
        bf_, f_gamma, f_beta, f_mean, f_var, out);
}

// Round 13
// 273.482 us; speedup vs baseline: 1.0540x; 1.0540x over previous
//
#include <hip/hip_runtime.h>
#include <math.h>

#define EPS 1e-5f

constexpr int Bb  = 128;
constexpr int C   = 256;
constexpr int Nz  = 169;   // 13*13
constexpr int Nx  = 625;   // 25*25
constexpr int NzP = 192;   // Nz padded (zero-filled)

typedef __bf16 bf16x8 __attribute__((ext_vector_type(8)));
typedef float  f32x4  __attribute__((ext_vector_type(4)));

__device__ __forceinline__ unsigned short f2bf(float f) {
    union { float f; unsigned u; } x; x.f = f;
    unsigned r = x.u + 0x7FFFu + ((x.u >> 16) & 1u);   // RNE
    return (unsigned short)(r >> 16);
}
__device__ __forceinline__ float bf2f(unsigned short h) {
    union { unsigned u; float f; } x; x.u = ((unsigned)h) << 16;
    return x.f;
}

// ---------------------------------------------------------------------------
// Wg, Wf → bf16
// ---------------------------------------------------------------------------
__global__ void cvt_wgf(const float* __restrict__ Wg, const float* __restrict__ Wf,
                        unsigned short* __restrict__ g, unsigned short* __restrict__ f)
{
    int i = blockIdx.x * 256 + threadIdx.x;
    if (i < C * C) g[i] = f2bf(Wg[i]);
    if (i < C * 2 * C) f[i] = f2bf(Wf[i]);
}

// ---------------------------------------------------------------------------
// wv = Wq^T bs, wu = Ws^T bq, c0 = bq.bs
// ---------------------------------------------------------------------------
__global__ void prep_small(const float* __restrict__ Wq, const float* __restrict__ Ws,
                           const float* __restrict__ bq, const float* __restrict__ bs,
                           float* __restrict__ wv, float* __restrict__ wu,
                           float* __restrict__ c0)
{
    const int tid = threadIdx.x;
    float a = 0.f, b = 0.f;
    for (int o = 0; o < C; ++o) {
        a += Wq[o * C + tid] * bs[o];
        b += Ws[o * C + tid] * bq[o];
    }
    wv[tid] = a;
    wu[tid] = b;
    if (tid == 0) {
        float c = 0.f;
        for (int o = 0; o < C; ++o) c += bq[o] * bs[o];
        c0[0] = c;
    }
}

// ---------------------------------------------------------------------------
// M = Wq^T Ws  (fp32 compute, split bf16 hi/lo output).  grid (4,4)
// ---------------------------------------------------------------------------
__global__ __launch_bounds__(256)
void m_gemm(const float* __restrict__ Wq, const float* __restrict__ Ws,
            unsigned short* __restrict__ Mhi, unsigned short* __restrict__ Mlo)
{
    __shared__ float Qs[16][65], Ss[16][65];
    const int j0 = blockIdx.x * 64, i0 = blockIdx.y * 64;
    const int tid = threadIdx.x, tx = tid & 15, ty = tid >> 4;
    float acc[4][4] = {};

    for (int kc = 0; kc < C; kc += 16) {
        #pragma unroll
        for (int i = 0; i < 4; ++i) {
            int e = tid + 256 * i;
            int k = e >> 6, col = e & 63;
            Qs[k][col] = Wq[(size_t)(kc + k) * C + i0 + col];
            Ss[k][col] = Ws[(size_t)(kc + k) * C + j0 + col];
        }
        __syncthreads();
        #pragma unroll
        for (int k = 0; k < 16; ++k) {
            float a[4], bv[4];
            #pragma unroll
            for (int i = 0; i < 4; ++i) a[i] = Qs[k][ty * 4 + i];
            #pragma unroll
            for (int j = 0; j < 4; ++j) bv[j] = Ss[k][tx * 4 + j];
            #pragma unroll
            for (int i = 0; i < 4; ++i)
                #pragma unroll
                for (int j = 0; j < 4; ++j)
                    acc[i][j] = fmaf(a[i], bv[j], acc[i][j]);
        }
        __syncthreads();
    }
    #pragma unroll
    for (int i = 0; i < 4; ++i)
        #pragma unroll
        for (int j = 0; j < 4; ++j) {
            float v = acc[i][j];
            unsigned short h = f2bf(v);
            size_t idx = (size_t)(i0 + ty * 4 + i) * C + j0 + tx * 4 + j;
            Mhi[idx] = h;
            Mlo[idx] = f2bf(v - bf2f(h));
        }
}

// ---------------------------------------------------------------------------
// u[b,m] = wu . zf[b,:,m] + c0
// ---------------------------------------------------------------------------
__global__ void bias_u(const float* __restrict__ zf, const float* __restrict__ wu,
                       const float* __restrict__ c0, float* __restrict__ U)
{
    const int b = blockIdx.x, m = threadIdx.x;
    if (m >= NzP) return;
    float s = 0.f;
    if (m < Nz) {
        const float* zb = zf + (size_t)b * C * Nz + m;
        float s0 = 0.f, s1 = 0.f, s2 = 0.f, s3 = 0.f;
        for (int c = 0; c < C; c += 4) {
            s0 += wu[c]     * zb[(size_t)c * Nz];
            s1 += wu[c + 1] * zb[(size_t)(c + 1) * Nz];
            s2 += wu[c + 2] * zb[(size_t)(c + 2) * Nz];
            s3 += wu[c + 3] * zb[(size_t)(c + 3) * Nz];
        }
        s = (s0 + s1) + (s2 + s3) + c0[0];
    }
    U[(size_t)b * NzP + m] = s;
}

// ---------------------------------------------------------------------------
// zf [b][C][Nz] f32  →  hi/lo bf16 [b][Nz][C]
// ---------------------------------------------------------------------------
__global__ __launch_bounds__(256)
void x2t_split(const float* __restrict__ X, unsigned short* __restrict__ Hi,
               unsigned short* __restrict__ Lo, int N)
{
    __shared__ float T[64][65];
    const int b = blockIdx.z, n0 = blockIdx.x * 64, c0 = blockIdx.y * 64;
    const float* Xb = X + ((size_t)b * C + c0) * N;
    #pragma unroll
    for (int i = 0; i < 16; ++i) {
        int e = threadIdx.x + 256 * i;
        int c = e >> 6, n = e & 63;
        T[c][n] = (n0 + n < N) ? Xb[(size_t)c * N + n0 + n] : 0.f;
    }
    __syncthreads();
    #pragma unroll
    for (int i = 0; i < 16; ++i) {
        int e = threadIdx.x + 256 * i;
        int n = e >> 6, c = e & 63;
        if (n0 + n < N) {
            float v = T[c][n];
            unsigned short h = f2bf(v);
            size_t idx = ((size_t)b * N + n0 + n) * C + c0 + c;
            Hi[idx] = h;
            Lo[idx] = f2bf(v - bf2f(h));
        }
    }
}

// ---------------------------------------------------------------------------
// Split-bf16 MFMA GEMM — z-side zq' = M zf + wv.
// ---------------------------------------------------------------------------
__global__ __launch_bounds__(256)
void mfma_split(const unsigned short* __restrict__ Ahi,
                const unsigned short* __restrict__ Alo, size_t aStride,
                const unsigned short* __restrict__ Bhi,
                const unsigned short* __restrict__ Blo,
                const float* __restrict__ bias,
                unsigned short* __restrict__ Yhi, unsigned short* __restrict__ Ylo,
                int N, int Nout, int K, int O)
{
    __shared__ unsigned short Ah[64][40], Al[64][40], Bh[64][40], Bl[64][40];

    const int b   = blockIdx.z;
    const int n0  = blockIdx.x * 64;
    const int o0  = blockIdx.y * 64;
    const int tid = threadIdx.x;
    const int lane = tid & 63, wid = tid >> 6;
    const int wr = wid >> 1, wc = wid & 1;

    const unsigned short* Ahb = Ahi + (size_t)b * aStride;
    const unsigned short* Alb = Alo + (size_t)b * aStride;
    const unsigned short* Bhb = Bhi + (size_t)b * N * K;
    const unsigned short* Blb = Blo + (size_t)b * N * K;

    f32x4 acc[2][2];
    #pragma unroll
    for (int i = 0; i < 2; ++i)
        #pragma unroll
        for (int j = 0; j < 2; ++j)
            #pragma unroll
            for (int e = 0; e < 4; ++e) acc[i][j][e] = 0.f;

    const int srow = tid >> 2, sseg = tid & 3;
    const int lr = lane & 15, lk = (lane >> 4) * 8;

    for (int kc = 0; kc < K; kc += 32) {
        const int gk = kc + sseg * 8;
        *(int4*)&Ah[srow][sseg * 8] = *(const int4*)&Ahb[(size_t)(o0 + srow) * K + gk];
        *(int4*)&Al[srow][sseg * 8] = *(const int4*)&Alb[(size_t)(o0 + srow) * K + gk];

        const int gn = n0 + srow;
        int4 bv = make_int4(0, 0, 0, 0), blv = make_int4(0, 0, 0, 0);
        if (gn < N) {
            bv  = *(const int4*)&Bhb[(size_t)gn * K + gk];
            blv = *(const int4*)&Blb[(size_t)gn * K + gk];
        }
        *(int4*)&Bh[srow][sseg * 8] = bv;
        *(int4*)&Bl[srow][sseg * 8] = blv;
        __syncthreads();

        bf16x8 ah[2], al[2], bh[2], bl[2];
        #pragma unroll
        for (int i = 0; i < 2; ++i) {
            ah[i] = *(const bf16x8*)&Ah[wr * 32 + i * 16 + lr][lk];
            al[i] = *(const bf16x8*)&Al[wr * 32 + i * 16 + lr][lk];
            bh[i] = *(const bf16x8*)&Bh[wc * 32 + i * 16 + lr][lk];
            bl[i] = *(const bf16x8*)&Bl[wc * 32 + i * 16 + lr][lk];
        }
        #pragma unroll
        for (int i = 0; i < 2; ++i)
            #pragma unroll
            for (int j = 0; j < 2; ++j) {
                acc[i][j] = __builtin_amdgcn_mfma_f32_16x16x32_bf16(al[i], bh[j], acc[i][j], 0, 0, 0);
                acc[i][j] = __builtin_amdgcn_mfma_f32_16x16x32_bf16(ah[i], bl[j], acc[i][j], 0, 0, 0);
                acc[i][j] = __builtin_amdgcn_mfma_f32_16x16x32_bf16(ah[i], bh[j], acc[i][j], 0, 0, 0);
            }
        __syncthreads();
    }

    const int lg = lane >> 4;
    #pragma unroll
    for (int i = 0; i < 2; ++i) {
        const int ob = o0 + wr * 32 + i * 16 + lg * 4;
        float bi[4];
        #pragma unroll
        for (int r = 0; r < 4; ++r) bi[r] = bias[ob + r];
        #pragma unroll
        for (int j = 0; j < 2; ++j) {
            const int gn = n0 + wc * 32 + j * 16 + lr;
            if (gn < Nout) {
                uint2 ph = make_uint2(0, 0), pl = make_uint2(0, 0);
                if (gn < N) {
                    unsigned short h[4], l[4];
                    #pragma unroll
                    for (int r = 0; r < 4; ++r) {
                        float v = acc[i][j][r] + bi[r];
                        h[r] = f2bf(v);
                        l[r] = f2bf(v - bf2f(h[r]));
                    }
                    ph.x = (unsigned)h[0] | ((unsigned)h[1] << 16);
                    ph.y = (unsigned)h[2] | ((unsigned)h[3] << 16);
                    pl.x = (unsigned)l[0] | ((unsigned)l[1] << 16);
                    pl.y = (unsigned)l[2] | ((unsigned)l[3] << 16);
                }
                size_t idx = ((size_t)b * Nout + gn) * O + ob;
                *(uint2*)&Yhi[idx] = ph;
                *(uint2*)&Ylo[idx] = pl;
            }
        }
    }
}

// ---------------------------------------------------------------------------
// Plain bf16 MFMA GEMM (z-side small: zf_g conv, zg2).
// ---------------------------------------------------------------------------
template<int MODE, int EPI>
__global__ __launch_bounds__(256)
void mfma_conv(const unsigned short* __restrict__ A, int aLd, size_t aStride,
               const unsigned short* __restrict__ B1,
               const float* __restrict__ bias, const float* __restrict__ gamma,
               const float* __restrict__ beta, const float* __restrict__ mean,
               const float* __restrict__ var,
               unsigned short* __restrict__ Y, int N, int Nout, int K, int O)
{
    __shared__ unsigned short As[64][40];
    __shared__ unsigned short Bs[64][40];

    const int b   = blockIdx.z;
    const int n0  = blockIdx.x * 64;
    const int o0  = blockIdx.y * 64;
    const int tid = threadIdx.x;
    const int lane = tid & 63, wid = tid >> 6;
    const int wr = wid >> 1, wc = wid & 1;

    const unsigned short* Ab  = A + (size_t)b * aStride;
    const unsigned short* B1b = B1 + (size_t)b * N * K;

    f32x4 acc[2][2];
    #pragma unroll
    for (int i = 0; i < 2; ++i)
        #pragma unroll
        for (int j = 0; j < 2; ++j)
            #pragma unroll
            for (int e = 0; e < 4; ++e) acc[i][j][e] = 0.f;

    const int srow = tid >> 2, sseg = tid & 3;
    const int lr = lane & 15, lk = (lane >> 4) * 8;

    for (int kc = 0; kc < K; kc += 32) {
        const int gk = kc + sseg * 8;
        *(int4*)&As[srow][sseg * 8] = *(const int4*)&Ab[(size_t)(o0 + srow) * aLd + gk];

        const int gn = n0 + srow;
        int4 bv = make_int4(0, 0, 0, 0);
        if (gn < N) bv = *(const int4*)&B1b[(size_t)gn * K + gk];
        *(int4*)&Bs[srow][sseg * 8] = bv;
        __syncthreads();

        bf16x8 a0 = *(const bf16x8*)&As[wr * 32 +      lr][lk];
        bf16x8 a1 = *(const bf16x8*)&As[wr * 32 + 16 + lr][lk];
        bf16x8 b0 = *(const bf16x8*)&Bs[wc * 32 +      lr][lk];
        bf16x8 b1 = *(const bf16x8*)&Bs[wc * 32 + 16 + lr][lk];

        acc[0][0] = __builtin_amdgcn_mfma_f32_16x16x32_bf16(a0, b0, acc[0][0], 0, 0, 0);
        acc[0][1] = __builtin_amdgcn_mfma_f32_16x16x32_bf16(a0, b1, acc[0][1], 0, 0, 0);
        acc[1][0] = __builtin_amdgcn_mfma_f32_16x16x32_bf16(a1, b0, acc[1][0], 0, 0, 0);
        acc[1][1] = __builtin_amdgcn_mfma_f32_16x16x32_bf16(a1, b1, acc[1][1], 0, 0, 0);
        __syncthreads();
    }

    const int lg = lane >> 4;
    #pragma unroll
    for (int i = 0; i < 2; ++i) {
        const int ob = o0 + wr * 32 + i * 16 + lg * 4;
        float inv[4], sh[4], bi[4];
        if (EPI) {
            #pragma unroll
            for (int r = 0; r < 4; ++r) {
                int o = ob + r;
                float iv = gamma[o] * rsqrtf(var[o] + EPS);
                inv[r] = iv; sh[r] = beta[o] - mean[o] * iv; bi[r] = bias[o];
            }
        }
        #pragma unroll
        for (int j = 0; j < 2; ++j) {
            const int gn = n0 + wc * 32 + j * 16 + lr;
            float v[4];
            #pragma unroll
            for (int r = 0; r < 4; ++r) {
                v[r] = acc[i][j][r];
                if (EPI) v[r] = fmaxf(fmaf(v[r] + bi[r], inv[r], sh[r]), 0.f);
            }
            if (MODE == 0) {
                if (gn < Nout) {
                    uint2 pk = make_uint2(0, 0);
                    if (gn < N) {
                        pk.x = (unsigned)f2bf(v[0]) | ((unsigned)f2bf(v[1]) << 16);
                        pk.y = (unsigned)f2bf(v[2]) | ((unsigned)f2bf(v[3]) << 16);
                    }
                    *(uint2*)&Y[((size_t)b * Nout + gn) * O + ob] = pk;
                }
            } else {
                if (gn < Nout) {
                    #pragma unroll
                    for (int r = 0; r < 4; ++r)
                        Y[((size_t)b * O + ob + r) * Nout + gn] =
                            (gn < N) ? f2bf(v[r]) : (unsigned short)0;
                }
            }
        }
    }
}

// ---------------------------------------------------------------------------
// X-side megakernel, per (b, 64-n tile).  Phase order: sim → sparsemax →
// G → P1 → P2.  A-operands (Wg, zg2, Wf2) are read as MFMA fragments
// DIRECTLY from global (L2-resident, k-contiguous 16B/lane) — no LDS
// staging, no barriers in P1/P2; G uses a double-buffered 5 KB xf staging
// (1 barrier/chunk).  acc is live only after sim → no parked registers.
// LDS 74.5 KB → 2 blocks/CU, no VGPR cap.
// ---------------------------------------------------------------------------
#define XGIDX(n, o) ((((n) << 8) + (o)) ^ (((n) & 7) << 3))

__global__ __launch_bounds__(256)
void mega_x(const float* __restrict__ Xf,
            const unsigned short* __restrict__ Zqh,   // [b][192][256]
            const unsigned short* __restrict__ Zql,
            const unsigned short* __restrict__ Wg,    // [256][256]
            const unsigned short* __restrict__ Zg2,   // [b][256][192]
            const unsigned short* __restrict__ Wf2,   // [256][512] base+256
            const float* __restrict__ U,              // [b][192]
            const float* __restrict__ bg, const float* __restrict__ g_gamma,
            const float* __restrict__ g_beta, const float* __restrict__ g_mean,
            const float* __restrict__ g_var,
            const float* __restrict__ bf, const float* __restrict__ f_gamma,
            const float* __restrict__ f_beta, const float* __restrict__ f_mean,
            const float* __restrict__ f_var,
            float* __restrict__ out)
{
    __shared__ __attribute__((aligned(16))) char pool[73728];
    __shared__ float Us[192];

    // overlays (phase-disjoint):
    unsigned short* Bzh = (unsigned short*)(pool);           // [192][40] sim B hi
    unsigned short* Bzl = (unsigned short*)(pool + 15360);   // [192][40] sim B lo
    unsigned short* Ssc = (unsigned short*)(pool);           // [64][200] scores (post-sim)
    unsigned short* XFh = (unsigned short*)(pool + 30720);   // [64][40] sim A hi
    unsigned short* XFl = (unsigned short*)(pool + 35840);   // [64][40] sim A lo
    unsigned short* XFg = (unsigned short*)(pool + 30720);   // 2x[64][40] G dbuf
    unsigned short* XG  = (unsigned short*)(pool + 40960);   // [64][256] swz

    // XCD-aware swizzle: 1280 blocks, 1280 % 8 == 0 -> bijective
    const int g0  = blockIdx.z * gridDim.x + blockIdx.x;
    const int rid = (g0 & 7) * 160 + (g0 >> 3);
    const int b   = rid / 10;
    const int n0  = (rid % 10) * 64;

    const int tid = threadIdx.x;
    const int lane = tid & 63, w = tid >> 6;
    const int lr = lane & 15, lg = lane >> 4, lk = lg * 8;
    const int brow = tid >> 2, bseg = tid & 3;

    const unsigned short* Zqhb = Zqh + (size_t)b * NzP * C;
    const unsigned short* Zqlb = Zql + (size_t)b * NzP * C;
    const unsigned short* Zg2b = Zg2 + (size_t)b * C * NzP;

    if (tid < 192) Us[tid] = U[(size_t)b * NzP + tid];

    // ================= sim phase =================
    {
        f32x4 sacc[12];
        #pragma unroll
        for (int j = 0; j < 12; ++j)
            #pragma unroll
            for (int e = 0; e < 4; ++e) sacc[j][e] = 0.f;

        for (int kc = 0; kc < C; kc += 32) {
            {
                const int gn = min(n0 + brow, Nx - 1);
                const float* src = Xf + ((size_t)b * C + kc + bseg * 8) * Nx + gn;
                unsigned short h[8], l[8];
                #pragma unroll
                for (int e = 0; e < 8; ++e) {
                    float v = src[(size_t)e * Nx];
                    h[e] = f2bf(v);
                    l[e] = f2bf(v - bf2f(h[e]));
                }
                uint4 ph, pl;
                ph.x = (unsigned)h[0] | ((unsigned)h[1] << 16);
                ph.y = (unsigned)h[2] | ((unsigned)h[3] << 16);
                ph.z = (unsigned)h[4] | ((unsigned)h[5] << 16);
                ph.w = (unsigned)h[6] | ((unsigned)h[7] << 16);
                pl.x = (unsigned)l[0] | ((unsigned)l[1] << 16);
                pl.y = (unsigned)l[2] | ((unsigned)l[3] << 16);
                pl.z = (unsigned)l[4] | ((unsigned)l[5] << 16);
                pl.w = (unsigned)l[6] | ((unsigned)l[7] << 16);
                *(uint4*)&XFh[brow * 40 + bseg * 8] = ph;
                *(uint4*)&XFl[brow * 40 + bseg * 8] = pl;
            }
            #pragma unroll
            for (int i = 0; i < 3; ++i) {
                const int slot = tid + 256 * i;
                const int r = slot >> 2, s = slot & 3;
                const int gk = kc + s * 8;
                *(int4*)&Bzh[r * 40 + s * 8] = *(const int4*)&Zqhb[(size_t)r * C + gk];
                *(int4*)&Bzl[r * 40 + s * 8] = *(const int4*)&Zqlb[(size_t)r * C + gk];
            }
            __syncthreads();

            bf16x8 a0h = *(const bf16x8*)&XFh[(w * 16 + lr) * 40 + lk];
            bf16x8 a0l = *(const bf16x8*)&XFl[(w * 16 + lr) * 40 + lk];
            #pragma unroll
            for (int j = 0; j < 12; ++j) {
                bf16x8 bh = *(const bf16x8*)&Bzh[(j * 16 + lr) * 40 + lk];
                bf16x8 bl = *(const bf16x8*)&Bzl[(j * 16 + lr) * 40 + lk];
                sacc[j] = __builtin_amdgcn_mfma_f32_16x16x32_bf16(a0l, bh, sacc[j], 0, 0, 0);
                sacc[j] = __builtin_amdgcn_mfma_f32_16x16x32_bf16(a0h, bl, sacc[j], 0, 0, 0);
                sacc[j] = __builtin_amdgcn_mfma_f32_16x16x32_bf16(a0h, bh, sacc[j], 0, 0, 0);
            }
            __syncthreads();
        }

        // add u[m], mask padded m
        #pragma unroll
        for (int j = 0; j < 12; ++j) {
            const int m = j * 16 + lr;
            const float uv = Us[m];
            const bool bad = (m >= Nz);
            #pragma unroll
            for (int q = 0; q < 4; ++q)
                sacc[j][q] = bad ? -1e30f : (sacc[j][q] + uv);
        }

        // row max over 12 regs + 16 lanes (m dimension)
        f32x4 mx = sacc[0];
        #pragma unroll
        for (int j = 1; j < 12; ++j)
            #pragma unroll
            for (int q = 0; q < 4; ++q) mx[q] = fmaxf(mx[q], sacc[j][q]);
        #pragma unroll
        for (int off = 1; off < 16; off <<= 1)
            #pragma unroll
            for (int q = 0; q < 4; ++q) mx[q] = fmaxf(mx[q], __shfl_xor(mx[q], off));

        // Newton on tau
        f32x4 tau;
        #pragma unroll
        for (int q = 0; q < 4; ++q) tau[q] = mx[q] - 1.0f;

        for (int it = 0; it < 16; ++it) {
            f32x4 s, cnt;
            #pragma unroll
            for (int q = 0; q < 4; ++q) { s[q] = 0.f; cnt[q] = 0.f; }
            #pragma unroll
            for (int j = 0; j < 12; ++j)
                #pragma unroll
                for (int q = 0; q < 4; ++q)
                    if (sacc[j][q] > tau[q]) { s[q] += sacc[j][q]; cnt[q] += 1.f; }
            #pragma unroll
            for (int off = 1; off < 16; off <<= 1)
                #pragma unroll
                for (int q = 0; q < 4; ++q) {
                    s[q]   += __shfl_xor(s[q], off);
                    cnt[q] += __shfl_xor(cnt[q], off);
                }
            bool adv = false;
            #pragma unroll
            for (int q = 0; q < 4; ++q) {
                float nt = (s[q] - 1.0f) / cnt[q];
                if (nt > tau[q]) { tau[q] = nt; adv = true; }
            }
            if (!__any(adv ? 1 : 0)) break;
        }

        // scores -> Ssc (overlays dead sim B staging; last sync was after MFMA)
        #pragma unroll
        for (int q = 0; q < 4; ++q) {
            const int n = w * 16 + 4 * lg + q;
            #pragma unroll
            for (int j = 0; j < 12; ++j) {
                const int m = j * 16 + lr;
                float sv = (m < Nz) ? fmaxf(sacc[j][q] - tau[q], 0.f) : 0.f;
                Ssc[n * 200 + m] = f2bf(sv);
            }
        }
    }

    // ================= G phase: acc = Wg . xf (A direct, xf dbuf) =========
    f32x4 acc[4][4];
    #pragma unroll
    for (int i = 0; i < 4; ++i)
        #pragma unroll
        for (int j = 0; j < 4; ++j)
            #pragma unroll
            for (int e = 0; e < 4; ++e) acc[i][j][e] = 0.f;

    // prologue: stage xf chunk 0 into buf 0
    {
        const int gn = min(n0 + brow, Nx - 1);
        const float* src = Xf + ((size_t)b * C + bseg * 8) * Nx + gn;
        unsigned short h[8];
        #pragma unroll
        for (int e = 0; e < 8; ++e) h[e] = f2bf(src[(size_t)e * Nx]);
        uint4 ph;
        ph.x = (unsigned)h[0] | ((unsigned)h[1] << 16);
        ph.y = (unsigned)h[2] | ((unsigned)h[3] << 16);
        ph.z = (unsigned)h[4] | ((unsigned)h[5] << 16);
        ph.w = (unsigned)h[6] | ((unsigned)h[7] << 16);
        *(uint4*)&XFg[brow * 40 + bseg * 8] = ph;
    }
    __syncthreads();   // Ssc + XFg buf0 ready

    #pragma unroll
    for (int c = 0; c < 8; ++c) {
        const int kc = c * 32;
        if (c < 7) {   // stage next chunk into other buffer
            const int gn = min(n0 + brow, Nx - 1);
            const float* src = Xf + ((size_t)b * C + kc + 32 + bseg * 8) * Nx + gn;
            unsigned short h[8];
            #pragma unroll
            for (int e = 0; e < 8; ++e) h[e] = f2bf(src[(size_t)e * Nx]);
            uint4 ph;
            ph.x = (unsigned)h[0] | ((unsigned)h[1] << 16);
            ph.y = (unsigned)h[2] | ((unsigned)h[3] << 16);
            ph.z = (unsigned)h[4] | ((unsigned)h[5] << 16);
            ph.w = (unsigned)h[6] | ((unsigned)h[7] << 16);
            *(uint4*)&XFg[((c + 1) & 1) * 2560 + brow * 40 + bseg * 8] = ph;
        }
        bf16x8 a[4], bfr[4];
        #pragma unroll
        for (int i = 0; i < 4; ++i)
            a[i] = *(const bf16x8*)&Wg[(size_t)(w * 64 + i * 16 + lr) * C + kc + lk];
        #pragma unroll
        for (int j = 0; j < 4; ++j)
            bfr[j] = *(const bf16x8*)&XFg[(c & 1) * 2560 + (j * 16 + lr) * 40 + lk];
        #pragma unroll
        for (int i = 0; i < 4; ++i)
            #pragma unroll
            for (int j = 0; j < 4; ++j)
                acc[i][j] = __builtin_amdgcn_mfma_f32_16x16x32_bf16(a[i], bfr[j], acc[i][j], 0, 0, 0);
        __syncthreads();
    }

    // G epilogue: bn_relu -> XG (XOR-swizzled), zero acc
    #pragma unroll
    for (int i = 0; i < 4; ++i) {
        const int ob = w * 64 + i * 16 + lg * 4;
        float inv[4], sh[4], bi[4];
        #pragma unroll
        for (int r = 0; r < 4; ++r) {
            int o = ob + r;
            float iv = g_gamma[o] * rsqrtf(g_var[o] + EPS);
            inv[r] = iv; sh[r] = g_beta[o] - g_mean[o] * iv; bi[r] = bg[o];
        }
        #pragma unroll
        for (int j = 0; j < 4; ++j) {
            const int n = j * 16 + lr;
            unsigned short h[4];
            #pragma unroll
            for (int r = 0; r < 4; ++r)
                h[r] = f2bf(fmaxf(fmaf(acc[i][j][r] + bi[r], inv[r], sh[r]), 0.f));
            uint2 pk;
            pk.x = (unsigned)h[0] | ((unsigned)h[1] << 16);
            pk.y = (unsigned)h[2] | ((unsigned)h[3] << 16);
            *(uint2*)&XG[XGIDX(n, ob)] = pk;
        }
    }
    #pragma unroll
    for (int i = 0; i < 4; ++i)
        #pragma unroll
        for (int j = 0; j < 4; ++j)
            #pragma unroll
            for (int e = 0; e < 4; ++e) acc[i][j][e] = 0.f;
    __syncthreads();   // XG visible; Ssc stable — no more barriers needed

    // ================= P1: acc += zg2 . Ssc (A direct, no barriers) =======
    #pragma unroll
    for (int c = 0; c < 6; ++c) {
        const int kc = c * 32;
        bf16x8 a[4], bfr[4];
        #pragma unroll
        for (int i = 0; i < 4; ++i)
            a[i] = *(const bf16x8*)&Zg2b[(size_t)(w * 64 + i * 16 + lr) * NzP + kc + lk];
        #pragma unroll
        for (int j = 0; j < 4; ++j)
            bfr[j] = *(const bf16x8*)&Ssc[(j * 16 + lr) * 200 + kc + lk];
        #pragma unroll
        for (int i = 0; i < 4; ++i)
            #pragma unroll
            for (int j = 0; j < 4; ++j)
                acc[i][j] = __builtin_amdgcn_mfma_f32_16x16x32_bf16(a[i], bfr[j], acc[i][j], 0, 0, 0);
    }

    // ================= P2: acc += Wf2 . XG (A direct, no barriers) =========
    #pragma unroll
    for (int c = 0; c < 8; ++c) {
        const int kc = c * 32;
        bf16x8 a[4], bfr[4];
        #pragma unroll
        for (int i = 0; i < 4; ++i)
            a[i] = *(const bf16x8*)&Wf2[(size_t)(w * 64 + i * 16 + lr) * 512 + kc + lk];
        #pragma unroll
        for (int j = 0; j < 4; ++j)
            bfr[j] = *(const bf16x8*)&XG[XGIDX(j * 16 + lr, kc + lk)];
        #pragma unroll
        for (int i = 0; i < 4; ++i)
            #pragma unroll
            for (int j = 0; j < 4; ++j)
                acc[i][j] = __builtin_amdgcn_mfma_f32_16x16x32_bf16(a[i], bfr[j], acc[i][j], 0, 0, 0);
    }

    // final epilogue: bn_relu(f) -> out f32 [b][256][Nx]
    #pragma unroll
    for (int i = 0; i < 4; ++i) {
        const int ob = w * 64 + i * 16 + lg * 4;
        float inv[4], sh[4], bi[4];
        #pragma unroll
        for (int r = 0; r < 4; ++r) {
            int o = ob + r;
            float iv = f_gamma[o] * rsqrtf(f_var[o] + EPS);
            inv[r] = iv; sh[r] = f_beta[o] - f_mean[o] * iv; bi[r] = bf[o];
        }
        #pragma unroll
        for (int j = 0; j < 4; ++j) {
            const int gn = n0 + j * 16 + lr;
            if (gn < Nx) {
                #pragma unroll
                for (int r = 0; r < 4; ++r) {
                    float v = fmaxf(fmaf(acc[i][j][r] + bi[r], inv[r], sh[r]), 0.f);
                    out[((size_t)b * C + ob + r) * Nx + gn] = v;
                }
            }
        }
    }
}

// ---------------------------------------------------------------------------
extern "C" void kernel_launch(void* const* d_in, const int* in_sizes, int n_in,
                              void* d_out, int out_size, void* d_ws, size_t ws_size,
                              hipStream_t stream)
{
    const float* zf      = (const float*)d_in[0];
    const float* xf      = (const float*)d_in[1];
    const float* Wq      = (const float*)d_in[2];
    const float* bq      = (const float*)d_in[3];
    const float* Ws_     = (const float*)d_in[4];
    const float* bs      = (const float*)d_in[5];
    const float* Wg      = (const float*)d_in[6];
    const float* bg      = (const float*)d_in[7];
    const float* g_gamma = (const float*)d_in[8];
    const float* g_beta  = (const float*)d_in[9];
    const float* g_mean  = (const float*)d_in[10];
    const float* g_var   = (const float*)d_in[11];
    const float* Wf      = (const float*)d_in[12];
    const float* bf_     = (const float*)d_in[13];
    const float* f_gamma = (const float*)d_in[14];
    const float* f_beta  = (const float*)d_in[15];
    const float* f_mean  = (const float*)d_in[16];
    const float* f_var   = (const float*)d_in[17];
    float* out = (float*)d_out;

    typedef unsigned short u16;
    char* ws = (char*)d_ws;
    u16*   zfT_hi = (u16*)(ws);                   //  11,075,584
    u16*   zfT_lo = (u16*)(ws +  11075584);       //  11,075,584
    u16*   zqT_hi = (u16*)(ws +  22151168);       //  12,582,912
    u16*   zqT_lo = (u16*)(ws +  34734080);       //  12,582,912
    u16*   zf_gT  = (u16*)(ws +  47316992);       //  12,582,912
    u16*   zg2    = (u16*)(ws +  59899904);       //  12,582,912
    float* U      = (float*)(ws +  72482816);     //      98,304
    u16*   Mhi    = (u16*)(ws +  72581120);       //     131,072
    u16*   Mlo    = (u16*)(ws +  72712192);       //     131,072
    u16*   Wg_bf  = (u16*)(ws +  72843264);       //     131,072
    u16*   Wf_bf  = (u16*)(ws +  72974336);       //     262,144
    float* wv     = (float*)(ws +  73236480);     //       1,024
    float* wu     = (float*)(ws +  73237504);     //       1,024
    float* c0     = (float*)(ws +  73238528);     //         256

    dim3 blk(256);
    const int gx_x = (Nx + 63) / 64;   // 10
    const int gx_z = NzP / 64;         // 3

    // small precomputes
    cvt_wgf<<<dim3((C * 2 * C + 255) / 256), blk, 0, stream>>>(Wg, Wf, Wg_bf, Wf_bf);
    prep_small<<<dim3(1), blk, 0, stream>>>(Wq, Ws_, bq, bs, wv, wu, c0);
    m_gemm<<<dim3(4, 4), blk, 0, stream>>>(Wq, Ws_, Mhi, Mlo);
    bias_u<<<dim3(Bb), blk, 0, stream>>>(zf, wu, c0, U);

    // z-side transpose/split
    x2t_split<<<dim3((Nz + 63) / 64, C / 64, Bb), blk, 0, stream>>>(zf, zfT_hi, zfT_lo, Nz);

    // zq' = M zf + wv  (split)
    mfma_split<<<dim3(gx_z, C / 64, Bb), blk, 0, stream>>>(
        Mhi, Mlo, 0, zfT_hi, zfT_lo, wv, zqT_hi, zqT_lo, Nz, NzP, C, C);

    // zf_g = bn_relu(Wg . zf)
    mfma_conv<0, 1><<<dim3(gx_z, C / 64, Bb), blk, 0, stream>>>(
        Wg_bf, C, 0, zfT_hi, bg, g_gamma, g_beta, g_mean, g_var,
        zf_gT, Nz, NzP, C, C);

    // zg2 = Wf1 . zf_g   -> [b][C][NzP] bf16
    mfma_conv<1, 0><<<dim3(gx_z, C / 64, Bb), blk, 0, stream>>>(
        Wf_bf, 2 * C, 0, zf_gT, nullptr, nullptr, nullptr, nullptr, nullptr,
        zg2, NzP, NzP, C, C);

    // x-side megakernel: sim + sparsemax + g-conv + final (P1+P2)
    mega_x<<<dim3(gx_x, 1, Bb), blk, 0, stream>>>(
        xf, zqT_hi, zqT_lo, Wg_bf, zg2, Wf_bf + C, U,
        bg, g_gamma, g_beta, g_mean, g_var,
        bf_, f_gamma, f_beta, f_mean, f_var, out);
}

// Round 14
// 210.625 us; speedup vs baseline: 1.3685x; 1.2984x over previous
//
#include <hip/hip_runtime.h>
#include <math.h>

#define EPS 1e-5f

constexpr int Bb  = 128;
constexpr int C   = 256;
constexpr int Nz  = 169;   // 13*13
constexpr int Nx  = 625;   // 25*25
constexpr int NzP = 192;   // Nz padded (zero-filled)

typedef __bf16 bf16x8 __attribute__((ext_vector_type(8)));
typedef float  f32x4  __attribute__((ext_vector_type(4)));

__device__ __forceinline__ unsigned short f2bf(float f) {
    union { float f; unsigned u; } x; x.f = f;
    unsigned r = x.u + 0x7FFFu + ((x.u >> 16) & 1u);   // RNE
    return (unsigned short)(r >> 16);
}
__device__ __forceinline__ float bf2f(unsigned short h) {
    union { unsigned u; float f; } x; x.u = ((unsigned)h) << 16;
    return x.f;
}

// ---------------------------------------------------------------------------
// prep_all: all mutually-independent precomputes in ONE launch,
// partitioned by blockIdx.x range:
//   [0,512)      : Wg,Wf -> bf16
//   512          : wv = Wq^T bs, wu = Ws^T bq, c0 = bq.bs
//   [513,529)    : M = Wq^T Ws (fp32, split bf16 out), 16 blocks
//   [529,657)    : U[b,m] = wu . zf[b,:,m] + c0, 128 blocks
//   [657,2193)   : zf -> zfT hi/lo transpose-split, 1536 blocks
// ---------------------------------------------------------------------------
__global__ __launch_bounds__(256)
void prep_all(const float* __restrict__ zf,
              const float* __restrict__ Wq, const float* __restrict__ bq,
              const float* __restrict__ Ws, const float* __restrict__ bs,
              const float* __restrict__ Wg, const float* __restrict__ Wf,
              unsigned short* __restrict__ Wg_bf, unsigned short* __restrict__ Wf_bf,
              float* __restrict__ wv, float* __restrict__ wu, float* __restrict__ c0,
              unsigned short* __restrict__ Mhi, unsigned short* __restrict__ Mlo,
              float* __restrict__ U,
              unsigned short* __restrict__ zfT_hi, unsigned short* __restrict__ zfT_lo)
{
    __shared__ float T[64][65];
    const int bx = blockIdx.x, tid = threadIdx.x;

    if (bx < 512) {
        // ---- weight conversion ----
        int i = bx * 256 + tid;
        if (i < C * C) Wg_bf[i] = f2bf(Wg[i]);
        if (i < C * 2 * C) Wf_bf[i] = f2bf(Wf[i]);
        return;
    }
    if (bx == 512) {
        // ---- small bias precomputes ----
        float a = 0.f, b = 0.f;
        for (int o = 0; o < C; ++o) {
            a += Wq[o * C + tid] * bs[o];
            b += Ws[o * C + tid] * bq[o];
        }
        wv[tid] = a;
        wu[tid] = b;
        if (tid == 0) {
            float c = 0.f;
            for (int o = 0; o < C; ++o) c += bq[o] * bs[o];
            c0[0] = c;
        }
        return;
    }
    if (bx < 529) {
        // ---- M = Wq^T Ws, 64x64 tile ----
        const int t  = bx - 513;
        const int j0 = (t & 3) * 64, i0 = (t >> 2) * 64;
        const int tx = tid & 15, ty = tid >> 4;
        float (*Qs)[65] = (float(*)[65])&T[0][0];
        float (*Ss)[65] = (float(*)[65])&T[16][0];
        float acc[4][4] = {};

        for (int kc = 0; kc < C; kc += 16) {
            #pragma unroll
            for (int i = 0; i < 4; ++i) {
                int e = tid + 256 * i;
                int k = e >> 6, col = e & 63;
                Qs[k][col] = Wq[(size_t)(kc + k) * C + i0 + col];
                Ss[k][col] = Ws[(size_t)(kc + k) * C + j0 + col];
            }
            __syncthreads();
            #pragma unroll
            for (int k = 0; k < 16; ++k) {
                float a[4], bv[4];
                #pragma unroll
                for (int i = 0; i < 4; ++i) a[i] = Qs[k][ty * 4 + i];
                #pragma unroll
                for (int j = 0; j < 4; ++j) bv[j] = Ss[k][tx * 4 + j];
                #pragma unroll
                for (int i = 0; i < 4; ++i)
                    #pragma unroll
                    for (int j = 0; j < 4; ++j)
                        acc[i][j] = fmaf(a[i], bv[j], acc[i][j]);
            }
            __syncthreads();
        }
        #pragma unroll
        for (int i = 0; i < 4; ++i)
            #pragma unroll
            for (int j = 0; j < 4; ++j) {
                float v = acc[i][j];
                unsigned short h = f2bf(v);
                size_t idx = (size_t)(i0 + ty * 4 + i) * C + j0 + tx * 4 + j;
                Mhi[idx] = h;
                Mlo[idx] = f2bf(v - bf2f(h));
            }
        return;
    }
    if (bx < 657) {
        // ---- U[b,m] ----
        const int b = bx - 529, m = tid;
        if (m >= NzP) return;
        float s = 0.f;
        if (m < Nz) {
            const float* zb = zf + (size_t)b * C * Nz + m;
            float s0 = 0.f, s1 = 0.f, s2 = 0.f, s3 = 0.f;
            for (int c = 0; c < C; c += 4) {
                s0 += wu[c]     * zb[(size_t)c * Nz];
                s1 += wu[c + 1] * zb[(size_t)(c + 1) * Nz];
                s2 += wu[c + 2] * zb[(size_t)(c + 2) * Nz];
                s3 += wu[c + 3] * zb[(size_t)(c + 3) * Nz];
            }
            s = (s0 + s1) + (s2 + s3) + c0[0];
        }
        U[(size_t)b * NzP + m] = s;
        return;
    }
    {
        // ---- zf transpose/split: [b][C][Nz] f32 -> [b][Nz][C] hi/lo ----
        const int t  = bx - 657;
        const int n0 = (t % 3) * 64;
        const int c0v = ((t / 3) & 3) * 64;
        const int b  = t / 12;
        const float* Xb = zf + ((size_t)b * C + c0v) * Nz;
        #pragma unroll
        for (int i = 0; i < 16; ++i) {
            int e = tid + 256 * i;
            int c = e >> 6, n = e & 63;
            T[c][n] = (n0 + n < Nz) ? Xb[(size_t)c * Nz + n0 + n] : 0.f;
        }
        __syncthreads();
        #pragma unroll
        for (int i = 0; i < 16; ++i) {
            int e = tid + 256 * i;
            int n = e >> 6, c = e & 63;
            if (n0 + n < Nz) {
                float v = T[c][n];
                unsigned short h = f2bf(v);
                size_t idx = ((size_t)b * Nz + n0 + n) * C + c0v + c;
                zfT_hi[idx] = h;
                zfT_lo[idx] = f2bf(v - bf2f(h));
            }
        }
    }
}

// ---------------------------------------------------------------------------
// z_gemm: per (n0, o0, b) block, computes BOTH
//   zq'  = M . zf + wv      (split x3 MFMA)  -> split bf16 [b][192][256]
//   zf_g = bn_relu(Wg . zf) (plain MFMA)     -> bf16       [b][192][256]
// sharing the zfT hi/lo B staging.
// ---------------------------------------------------------------------------
__global__ __launch_bounds__(256)
void z_gemm(const unsigned short* __restrict__ Mhi,
            const unsigned short* __restrict__ Mlo,
            const unsigned short* __restrict__ Wg,
            const unsigned short* __restrict__ Bhi,
            const unsigned short* __restrict__ Blo,
            const float* __restrict__ wv,
            const float* __restrict__ bg, const float* __restrict__ g_gamma,
            const float* __restrict__ g_beta, const float* __restrict__ g_mean,
            const float* __restrict__ g_var,
            unsigned short* __restrict__ Yqh, unsigned short* __restrict__ Yql,
            unsigned short* __restrict__ Yg)
{
    __shared__ unsigned short Ah[64][40], Al[64][40], Ag[64][40];
    __shared__ unsigned short Bh[64][40], Bl[64][40];

    const int b   = blockIdx.z;
    const int n0  = blockIdx.x * 64;
    const int o0  = blockIdx.y * 64;
    const int tid = threadIdx.x;
    const int lane = tid & 63, wid = tid >> 6;
    const int wr = wid >> 1, wc = wid & 1;

    const unsigned short* Bhb = Bhi + (size_t)b * Nz * C;
    const unsigned short* Blb = Blo + (size_t)b * Nz * C;

    f32x4 accq[2][2], accg[2][2];
    #pragma unroll
    for (int i = 0; i < 2; ++i)
        #pragma unroll
        for (int j = 0; j < 2; ++j)
            #pragma unroll
            for (int e = 0; e < 4; ++e) { accq[i][j][e] = 0.f; accg[i][j][e] = 0.f; }

    const int srow = tid >> 2, sseg = tid & 3;
    const int lr = lane & 15, lk = (lane >> 4) * 8;

    for (int kc = 0; kc < C; kc += 32) {
        const int gk = kc + sseg * 8;
        *(int4*)&Ah[srow][sseg * 8] = *(const int4*)&Mhi[(size_t)(o0 + srow) * C + gk];
        *(int4*)&Al[srow][sseg * 8] = *(const int4*)&Mlo[(size_t)(o0 + srow) * C + gk];
        *(int4*)&Ag[srow][sseg * 8] = *(const int4*)&Wg[(size_t)(o0 + srow) * C + gk];

        const int gn = n0 + srow;
        int4 bv = make_int4(0, 0, 0, 0), blv = make_int4(0, 0, 0, 0);
        if (gn < Nz) {
            bv  = *(const int4*)&Bhb[(size_t)gn * C + gk];
            blv = *(const int4*)&Blb[(size_t)gn * C + gk];
        }
        *(int4*)&Bh[srow][sseg * 8] = bv;
        *(int4*)&Bl[srow][sseg * 8] = blv;
        __syncthreads();

        bf16x8 ah[2], al[2], ag[2], bh[2], bl[2];
        #pragma unroll
        for (int i = 0; i < 2; ++i) {
            ah[i] = *(const bf16x8*)&Ah[wr * 32 + i * 16 + lr][lk];
            al[i] = *(const bf16x8*)&Al[wr * 32 + i * 16 + lr][lk];
            ag[i] = *(const bf16x8*)&Ag[wr * 32 + i * 16 + lr][lk];
            bh[i] = *(const bf16x8*)&Bh[wc * 32 + i * 16 + lr][lk];
            bl[i] = *(const bf16x8*)&Bl[wc * 32 + i * 16 + lr][lk];
        }
        #pragma unroll
        for (int i = 0; i < 2; ++i)
            #pragma unroll
            for (int j = 0; j < 2; ++j) {
                accq[i][j] = __builtin_amdgcn_mfma_f32_16x16x32_bf16(al[i], bh[j], accq[i][j], 0, 0, 0);
                accq[i][j] = __builtin_amdgcn_mfma_f32_16x16x32_bf16(ah[i], bl[j], accq[i][j], 0, 0, 0);
                accq[i][j] = __builtin_amdgcn_mfma_f32_16x16x32_bf16(ah[i], bh[j], accq[i][j], 0, 0, 0);
                accg[i][j] = __builtin_amdgcn_mfma_f32_16x16x32_bf16(ag[i], bh[j], accg[i][j], 0, 0, 0);
            }
        __syncthreads();
    }

    const int lg = lane >> 4;
    #pragma unroll
    for (int i = 0; i < 2; ++i) {
        const int ob = o0 + wr * 32 + i * 16 + lg * 4;
        float bi[4], inv[4], sh[4], bgi[4];
        #pragma unroll
        for (int r = 0; r < 4; ++r) {
            int o = ob + r;
            bi[r] = wv[o];
            float iv = g_gamma[o] * rsqrtf(g_var[o] + EPS);
            inv[r] = iv; sh[r] = g_beta[o] - g_mean[o] * iv; bgi[r] = bg[o];
        }
        #pragma unroll
        for (int j = 0; j < 2; ++j) {
            const int gn = n0 + wc * 32 + j * 16 + lr;
            // zq' split write
            uint2 ph = make_uint2(0, 0), pl = make_uint2(0, 0), pg = make_uint2(0, 0);
            if (gn < Nz) {
                unsigned short h[4], l[4], g[4];
                #pragma unroll
                for (int r = 0; r < 4; ++r) {
                    float v = accq[i][j][r] + bi[r];
                    h[r] = f2bf(v);
                    l[r] = f2bf(v - bf2f(h[r]));
                    g[r] = f2bf(fmaxf(fmaf(accg[i][j][r] + bgi[r], inv[r], sh[r]), 0.f));
                }
                ph.x = (unsigned)h[0] | ((unsigned)h[1] << 16);
                ph.y = (unsigned)h[2] | ((unsigned)h[3] << 16);
                pl.x = (unsigned)l[0] | ((unsigned)l[1] << 16);
                pl.y = (unsigned)l[2] | ((unsigned)l[3] << 16);
                pg.x = (unsigned)g[0] | ((unsigned)g[1] << 16);
                pg.y = (unsigned)g[2] | ((unsigned)g[3] << 16);
            }
            size_t idx = ((size_t)b * NzP + gn) * C + ob;
            *(uint2*)&Yqh[idx] = ph;
            *(uint2*)&Yql[idx] = pl;
            *(uint2*)&Yg[idx]  = pg;
        }
    }
}

// ---------------------------------------------------------------------------
// Plain bf16 MFMA GEMM — zg2 = Wf1 . zf_g  -> [b][O][Nout] bf16
// ---------------------------------------------------------------------------
__global__ __launch_bounds__(256)
void zg2_gemm(const unsigned short* __restrict__ A, int aLd,
              const unsigned short* __restrict__ B1,
              unsigned short* __restrict__ Y, int N, int Nout, int K, int O)
{
    __shared__ unsigned short As[64][40];
    __shared__ unsigned short Bs[64][40];

    const int b   = blockIdx.z;
    const int n0  = blockIdx.x * 64;
    const int o0  = blockIdx.y * 64;
    const int tid = threadIdx.x;
    const int lane = tid & 63, wid = tid >> 6;
    const int wr = wid >> 1, wc = wid & 1;

    const unsigned short* B1b = B1 + (size_t)b * N * K;

    f32x4 acc[2][2];
    #pragma unroll
    for (int i = 0; i < 2; ++i)
        #pragma unroll
        for (int j = 0; j < 2; ++j)
            #pragma unroll
            for (int e = 0; e < 4; ++e) acc[i][j][e] = 0.f;

    const int srow = tid >> 2, sseg = tid & 3;
    const int lr = lane & 15, lk = (lane >> 4) * 8;

    for (int kc = 0; kc < K; kc += 32) {
        const int gk = kc + sseg * 8;
        *(int4*)&As[srow][sseg * 8] = *(const int4*)&A[(size_t)(o0 + srow) * aLd + gk];

        const int gn = n0 + srow;
        int4 bv = make_int4(0, 0, 0, 0);
        if (gn < N) bv = *(const int4*)&B1b[(size_t)gn * K + gk];
        *(int4*)&Bs[srow][sseg * 8] = bv;
        __syncthreads();

        bf16x8 a0 = *(const bf16x8*)&As[wr * 32 +      lr][lk];
        bf16x8 a1 = *(const bf16x8*)&As[wr * 32 + 16 + lr][lk];
        bf16x8 b0 = *(const bf16x8*)&Bs[wc * 32 +      lr][lk];
        bf16x8 b1 = *(const bf16x8*)&Bs[wc * 32 + 16 + lr][lk];

        acc[0][0] = __builtin_amdgcn_mfma_f32_16x16x32_bf16(a0, b0, acc[0][0], 0, 0, 0);
        acc[0][1] = __builtin_amdgcn_mfma_f32_16x16x32_bf16(a0, b1, acc[0][1], 0, 0, 0);
        acc[1][0] = __builtin_amdgcn_mfma_f32_16x16x32_bf16(a1, b0, acc[1][0], 0, 0, 0);
        acc[1][1] = __builtin_amdgcn_mfma_f32_16x16x32_bf16(a1, b1, acc[1][1], 0, 0, 0);
        __syncthreads();
    }

    const int lg = lane >> 4;
    #pragma unroll
    for (int i = 0; i < 2; ++i) {
        const int ob = o0 + wr * 32 + i * 16 + lg * 4;
        #pragma unroll
        for (int j = 0; j < 2; ++j) {
            const int gn = n0 + wc * 32 + j * 16 + lr;
            if (gn < Nout) {
                #pragma unroll
                for (int r = 0; r < 4; ++r)
                    Y[((size_t)b * O + ob + r) * Nout + gn] =
                        (gn < N) ? f2bf(acc[i][j][r]) : (unsigned short)0;
            }
        }
    }
}

// ---------------------------------------------------------------------------
// X-side megakernel (unchanged from round 13).
// ---------------------------------------------------------------------------
#define XGIDX(n, o) ((((n) << 8) + (o)) ^ (((n) & 7) << 3))

__global__ __launch_bounds__(256)
void mega_x(const float* __restrict__ Xf,
            const unsigned short* __restrict__ Zqh,   // [b][192][256]
            const unsigned short* __restrict__ Zql,
            const unsigned short* __restrict__ Wg,    // [256][256]
            const unsigned short* __restrict__ Zg2,   // [b][256][192]
            const unsigned short* __restrict__ Wf2,   // [256][512] base+256
            const float* __restrict__ U,              // [b][192]
            const float* __restrict__ bg, const float* __restrict__ g_gamma,
            const float* __restrict__ g_beta, const float* __restrict__ g_mean,
            const float* __restrict__ g_var,
            const float* __restrict__ bf, const float* __restrict__ f_gamma,
            const float* __restrict__ f_beta, const float* __restrict__ f_mean,
            const float* __restrict__ f_var,
            float* __restrict__ out)
{
    __shared__ __attribute__((aligned(16))) char pool[73728];
    __shared__ float Us[192];

    unsigned short* Bzh = (unsigned short*)(pool);           // [192][40] sim B hi
    unsigned short* Bzl = (unsigned short*)(pool + 15360);   // [192][40] sim B lo
    unsigned short* Ssc = (unsigned short*)(pool);           // [64][200] scores (post-sim)
    unsigned short* XFh = (unsigned short*)(pool + 30720);   // [64][40] sim A hi
    unsigned short* XFl = (unsigned short*)(pool + 35840);   // [64][40] sim A lo
    unsigned short* XFg = (unsigned short*)(pool + 30720);   // 2x[64][40] G dbuf
    unsigned short* XG  = (unsigned short*)(pool + 40960);   // [64][256] swz

    const int g0  = blockIdx.z * gridDim.x + blockIdx.x;
    const int rid = (g0 & 7) * 160 + (g0 >> 3);
    const int b   = rid / 10;
    const int n0  = (rid % 10) * 64;

    const int tid = threadIdx.x;
    const int lane = tid & 63, w = tid >> 6;
    const int lr = lane & 15, lg = lane >> 4, lk = lg * 8;
    const int brow = tid >> 2, bseg = tid & 3;

    const unsigned short* Zqhb = Zqh + (size_t)b * NzP * C;
    const unsigned short* Zqlb = Zql + (size_t)b * NzP * C;
    const unsigned short* Zg2b = Zg2 + (size_t)b * C * NzP;

    if (tid < 192) Us[tid] = U[(size_t)b * NzP + tid];

    // ================= sim phase =================
    {
        f32x4 sacc[12];
        #pragma unroll
        for (int j = 0; j < 12; ++j)
            #pragma unroll
            for (int e = 0; e < 4; ++e) sacc[j][e] = 0.f;

        for (int kc = 0; kc < C; kc += 32) {
            {
                const int gn = min(n0 + brow, Nx - 1);
                const float* src = Xf + ((size_t)b * C + kc + bseg * 8) * Nx + gn;
                unsigned short h[8], l[8];
                #pragma unroll
                for (int e = 0; e < 8; ++e) {
                    float v = src[(size_t)e * Nx];
                    h[e] = f2bf(v);
                    l[e] = f2bf(v - bf2f(h[e]));
                }
                uint4 ph, pl;
                ph.x = (unsigned)h[0] | ((unsigned)h[1] << 16);
                ph.y = (unsigned)h[2] | ((unsigned)h[3] << 16);
                ph.z = (unsigned)h[4] | ((unsigned)h[5] << 16);
                ph.w = (unsigned)h[6] | ((unsigned)h[7] << 16);
                pl.x = (unsigned)l[0] | ((unsigned)l[1] << 16);
                pl.y = (unsigned)l[2] | ((unsigned)l[3] << 16);
                pl.z = (unsigned)l[4] | ((unsigned)l[5] << 16);
                pl.w = (unsigned)l[6] | ((unsigned)l[7] << 16);
                *(uint4*)&XFh[brow * 40 + bseg * 8] = ph;
                *(uint4*)&XFl[brow * 40 + bseg * 8] = pl;
            }
            #pragma unroll
            for (int i = 0; i < 3; ++i) {
                const int slot = tid + 256 * i;
                const int r = slot >> 2, s = slot & 3;
                const int gk = kc + s * 8;
                *(int4*)&Bzh[r * 40 + s * 8] = *(const int4*)&Zqhb[(size_t)r * C + gk];
                *(int4*)&Bzl[r * 40 + s * 8] = *(const int4*)&Zqlb[(size_t)r * C + gk];
            }
            __syncthreads();

            bf16x8 a0h = *(const bf16x8*)&XFh[(w * 16 + lr) * 40 + lk];
            bf16x8 a0l = *(const bf16x8*)&XFl[(w * 16 + lr) * 40 + lk];
            #pragma unroll
            for (int j = 0; j < 12; ++j) {
                bf16x8 bh = *(const bf16x8*)&Bzh[(j * 16 + lr) * 40 + lk];
                bf16x8 bl = *(const bf16x8*)&Bzl[(j * 16 + lr) * 40 + lk];
                sacc[j] = __builtin_amdgcn_mfma_f32_16x16x32_bf16(a0l, bh, sacc[j], 0, 0, 0);
                sacc[j] = __builtin_amdgcn_mfma_f32_16x16x32_bf16(a0h, bl, sacc[j], 0, 0, 0);
                sacc[j] = __builtin_amdgcn_mfma_f32_16x16x32_bf16(a0h, bh, sacc[j], 0, 0, 0);
            }
            __syncthreads();
        }

        #pragma unroll
        for (int j = 0; j < 12; ++j) {
            const int m = j * 16 + lr;
            const float uv = Us[m];
            const bool bad = (m >= Nz);
            #pragma unroll
            for (int q = 0; q < 4; ++q)
                sacc[j][q] = bad ? -1e30f : (sacc[j][q] + uv);
        }

        f32x4 mx = sacc[0];
        #pragma unroll
        for (int j = 1; j < 12; ++j)
            #pragma unroll
            for (int q = 0; q < 4; ++q) mx[q] = fmaxf(mx[q], sacc[j][q]);
        #pragma unroll
        for (int off = 1; off < 16; off <<= 1)
            #pragma unroll
            for (int q = 0; q < 4; ++q) mx[q] = fmaxf(mx[q], __shfl_xor(mx[q], off));

        f32x4 tau;
        #pragma unroll
        for (int q = 0; q < 4; ++q) tau[q] = mx[q] - 1.0f;

        for (int it = 0; it < 16; ++it) {
            f32x4 s, cnt;
            #pragma unroll
            for (int q = 0; q < 4; ++q) { s[q] = 0.f; cnt[q] = 0.f; }
            #pragma unroll
            for (int j = 0; j < 12; ++j)
                #pragma unroll
                for (int q = 0; q < 4; ++q)
                    if (sacc[j][q] > tau[q]) { s[q] += sacc[j][q]; cnt[q] += 1.f; }
            #pragma unroll
            for (int off = 1; off < 16; off <<= 1)
                #pragma unroll
                for (int q = 0; q < 4; ++q) {
                    s[q]   += __shfl_xor(s[q], off);
                    cnt[q] += __shfl_xor(cnt[q], off);
                }
            bool adv = false;
            #pragma unroll
            for (int q = 0; q < 4; ++q) {
                float nt = (s[q] - 1.0f) / cnt[q];
                if (nt > tau[q]) { tau[q] = nt; adv = true; }
            }
            if (!__any(adv ? 1 : 0)) break;
        }

        #pragma unroll
        for (int q = 0; q < 4; ++q) {
            const int n = w * 16 + 4 * lg + q;
            #pragma unroll
            for (int j = 0; j < 12; ++j) {
                const int m = j * 16 + lr;
                float sv = (m < Nz) ? fmaxf(sacc[j][q] - tau[q], 0.f) : 0.f;
                Ssc[n * 200 + m] = f2bf(sv);
            }
        }
    }

    // ================= G phase =================
    f32x4 acc[4][4];
    #pragma unroll
    for (int i = 0; i < 4; ++i)
        #pragma unroll
        for (int j = 0; j < 4; ++j)
            #pragma unroll
            for (int e = 0; e < 4; ++e) acc[i][j][e] = 0.f;

    {
        const int gn = min(n0 + brow, Nx - 1);
        const float* src = Xf + ((size_t)b * C + bseg * 8) * Nx + gn;
        unsigned short h[8];
        #pragma unroll
        for (int e = 0; e < 8; ++e) h[e] = f2bf(src[(size_t)e * Nx]);
        uint4 ph;
        ph.x = (unsigned)h[0] | ((unsigned)h[1] << 16);
        ph.y = (unsigned)h[2] | ((unsigned)h[3] << 16);
        ph.z = (unsigned)h[4] | ((unsigned)h[5] << 16);
        ph.w = (unsigned)h[6] | ((unsigned)h[7] << 16);
        *(uint4*)&XFg[brow * 40 + bseg * 8] = ph;
    }
    __syncthreads();

    #pragma unroll
    for (int c = 0; c < 8; ++c) {
        const int kc = c * 32;
        if (c < 7) {
            const int gn = min(n0 + brow, Nx - 1);
            const float* src = Xf + ((size_t)b * C + kc + 32 + bseg * 8) * Nx + gn;
            unsigned short h[8];
            #pragma unroll
            for (int e = 0; e < 8; ++e) h[e] = f2bf(src[(size_t)e * Nx]);
            uint4 ph;
            ph.x = (unsigned)h[0] | ((unsigned)h[1] << 16);
            ph.y = (unsigned)h[2] | ((unsigned)h[3] << 16);
            ph.z = (unsigned)h[4] | ((unsigned)h[5] << 16);
            ph.w = (unsigned)h[6] | ((unsigned)h[7] << 16);
            *(uint4*)&XFg[((c + 1) & 1) * 2560 + brow * 40 + bseg * 8] = ph;
        }
        bf16x8 a[4], bfr[4];
        #pragma unroll
        for (int i = 0; i < 4; ++i)
            a[i] = *(const bf16x8*)&Wg[(size_t)(w * 64 + i * 16 + lr) * C + kc + lk];
        #pragma unroll
        for (int j = 0; j < 4; ++j)
            bfr[j] = *(const bf16x8*)&XFg[(c & 1) * 2560 + (j * 16 + lr) * 40 + lk];
        #pragma unroll
        for (int i = 0; i < 4; ++i)
            #pragma unroll
            for (int j = 0; j < 4; ++j)
                acc[i][j] = __builtin_amdgcn_mfma_f32_16x16x32_bf16(a[i], bfr[j], acc[i][j], 0, 0, 0);
        __syncthreads();
    }

    #pragma unroll
    for (int i = 0; i < 4; ++i) {
        const int ob = w * 64 + i * 16 + lg * 4;
        float inv[4], sh[4], bi[4];
        #pragma unroll
        for (int r = 0; r < 4; ++r) {
            int o = ob + r;
            float iv = g_gamma[o] * rsqrtf(g_var[o] + EPS);
            inv[r] = iv; sh[r] = g_beta[o] - g_mean[o] * iv; bi[r] = bg[o];
        }
        #pragma unroll
        for (int j = 0; j < 4; ++j) {
            const int n = j * 16 + lr;
            unsigned short h[4];
            #pragma unroll
            for (int r = 0; r < 4; ++r)
                h[r] = f2bf(fmaxf(fmaf(acc[i][j][r] + bi[r], inv[r], sh[r]), 0.f));
            uint2 pk;
            pk.x = (unsigned)h[0] | ((unsigned)h[1] << 16);
            pk.y = (unsigned)h[2] | ((unsigned)h[3] << 16);
            *(uint2*)&XG[XGIDX(n, ob)] = pk;
        }
    }
    #pragma unroll
    for (int i = 0; i < 4; ++i)
        #pragma unroll
        for (int j = 0; j < 4; ++j)
            #pragma unroll
            for (int e = 0; e < 4; ++e) acc[i][j][e] = 0.f;
    __syncthreads();

    // ================= P1 =================
    #pragma unroll
    for (int c = 0; c < 6; ++c) {
        const int kc = c * 32;
        bf16x8 a[4], bfr[4];
        #pragma unroll
        for (int i = 0; i < 4; ++i)
            a[i] = *(const bf16x8*)&Zg2b[(size_t)(w * 64 + i * 16 + lr) * NzP + kc + lk];
        #pragma unroll
        for (int j = 0; j < 4; ++j)
            bfr[j] = *(const bf16x8*)&Ssc[(j * 16 + lr) * 200 + kc + lk];
        #pragma unroll
        for (int i = 0; i < 4; ++i)
            #pragma unroll
            for (int j = 0; j < 4; ++j)
                acc[i][j] = __builtin_amdgcn_mfma_f32_16x16x32_bf16(a[i], bfr[j], acc[i][j], 0, 0, 0);
    }

    // ================= P2 =================
    #pragma unroll
    for (int c = 0; c < 8; ++c) {
        const int kc = c * 32;
        bf16x8 a[4], bfr[4];
        #pragma unroll
        for (int i = 0; i < 4; ++i)
            a[i] = *(const bf16x8*)&Wf2[(size_t)(w * 64 + i * 16 + lr) * 512 + kc + lk];
        #pragma unroll
        for (int j = 0; j < 4; ++j)
            bfr[j] = *(const bf16x8*)&XG[XGIDX(j * 16 + lr, kc + lk)];
        #pragma unroll
        for (int i = 0; i < 4; ++i)
            #pragma unroll
            for (int j = 0; j < 4; ++j)
                acc[i][j] = __builtin_amdgcn_mfma_f32_16x16x32_bf16(a[i], bfr[j], acc[i][j], 0, 0, 0);
    }

    // final epilogue
    #pragma unroll
    for (int i = 0; i < 4; ++i) {
        const int ob = w * 64 + i * 16 + lg * 4;
        float inv[4], sh[4], bi[4];
        #pragma unroll
        for (int r = 0; r < 4; ++r) {
            int o = ob + r;
            float iv = f_gamma[o] * rsqrtf(f_var[o] + EPS);
            inv[r] = iv; sh[r] = f_beta[o] - f_mean[o] * iv; bi[r] = bf[o];
        }
        #pragma unroll
        for (int j = 0; j < 4; ++j) {
            const int gn = n0 + j * 16 + lr;
            if (gn < Nx) {
                #pragma unroll
                for (int r = 0; r < 4; ++r) {
                    float v = fmaxf(fmaf(acc[i][j][r] + bi[r], inv[r], sh[r]), 0.f);
                    out[((size_t)b * C + ob + r) * Nx + gn] = v;
                }
            }
        }
    }
}

// ---------------------------------------------------------------------------
extern "C" void kernel_launch(void* const* d_in, const int* in_sizes, int n_in,
                              void* d_out, int out_size, void* d_ws, size_t ws_size,
                              hipStream_t stream)
{
    const float* zf      = (const float*)d_in[0];
    const float* xf      = (const float*)d_in[1];
    const float* Wq      = (const float*)d_in[2];
    const float* bq      = (const float*)d_in[3];
    const float* Ws_     = (const float*)d_in[4];
    const float* bs      = (const float*)d_in[5];
    const float* Wg      = (const float*)d_in[6];
    const float* bg      = (const float*)d_in[7];
    const float* g_gamma = (const float*)d_in[8];
    const float* g_beta  = (const float*)d_in[9];
    const float* g_mean  = (const float*)d_in[10];
    const float* g_var   = (const float*)d_in[11];
    const float* Wf      = (const float*)d_in[12];
    const float* bf_     = (const float*)d_in[13];
    const float* f_gamma = (const float*)d_in[14];
    const float* f_beta  = (const float*)d_in[15];
    const float* f_mean  = (const float*)d_in[16];
    const float* f_var   = (const float*)d_in[17];
    float* out = (float*)d_out;

    typedef unsigned short u16;
    char* ws = (char*)d_ws;
    u16*   zfT_hi = (u16*)(ws);                   //  11,075,584
    u16*   zfT_lo = (u16*)(ws +  11075584);       //  11,075,584
    u16*   zqT_hi = (u16*)(ws +  22151168);       //  12,582,912
    u16*   zqT_lo = (u16*)(ws +  34734080);       //  12,582,912
    u16*   zf_gT  = (u16*)(ws +  47316992);       //  12,582,912
    u16*   zg2    = (u16*)(ws +  59899904);       //  12,582,912
    float* U      = (float*)(ws +  72482816);     //      98,304
    u16*   Mhi    = (u16*)(ws +  72581120);       //     131,072
    u16*   Mlo    = (u16*)(ws +  72712192);       //     131,072
    u16*   Wg_bf  = (u16*)(ws +  72843264);       //     131,072
    u16*   Wf_bf  = (u16*)(ws +  72974336);       //     262,144
    float* wv     = (float*)(ws +  73236480);     //       1,024
    float* wu     = (float*)(ws +  73237504);     //       1,024
    float* c0     = (float*)(ws +  73238528);     //         256

    dim3 blk(256);
    const int gx_x = (Nx + 63) / 64;   // 10
    const int gx_z = NzP / 64;         // 3

    // 1) all independent precomputes in one launch
    prep_all<<<dim3(2193), blk, 0, stream>>>(
        zf, Wq, bq, Ws_, bs, Wg, Wf,
        Wg_bf, Wf_bf, wv, wu, c0, Mhi, Mlo, U, zfT_hi, zfT_lo);

    // 2) zq' (split) + zf_g (plain) fused, shared B staging
    z_gemm<<<dim3(gx_z, C / 64, Bb), blk, 0, stream>>>(
        Mhi, Mlo, Wg_bf, zfT_hi, zfT_lo, wv,
        bg, g_gamma, g_beta, g_mean, g_var,
        zqT_hi, zqT_lo, zf_gT);

    // 3) zg2 = Wf1 . zf_g   -> [b][C][NzP] bf16
    zg2_gemm<<<dim3(gx_z, C / 64, Bb), blk, 0, stream>>>(
        Wf_bf, 2 * C, zf_gT, zg2, NzP, NzP, C, C);

    // 4) x-side megakernel
    mega_x<<<dim3(gx_x, 1, Bb), blk, 0, stream>>>(
        xf, zqT_hi, zqT_lo, Wg_bf, zg2, Wf_bf + C, U,
        bg, g_gamma, g_beta, g_mean, g_var,
        bf_, f_gamma, f_beta, f_mean, f_var, out);
}